// Round 1
// baseline (3517.221 us; speedup 1.0000x reference)
//
#include <hip/hip_runtime.h>
#include <math.h>

#define BB 4
#define CC 64
#define HH 256
#define WW 256
#define WF 129
#define NPIX (WF*HH)                 // 33024
#define NS ((size_t)BB*CC*NPIX)      // 8454144 floats per plane-set
#define TWOPI 6.283185307179586f

// ---------------- four-step 256-point complex FFT in LDS ----------------
__device__ __forceinline__ float2 cmulf(float2 a, float2 b) {
    return make_float2(a.x*b.x - a.y*b.y, a.x*b.y + a.y*b.x);
}

template<int SIGN>
__device__ __forceinline__ float2 fft256_lds(const float2* __restrict__ xs,
                                             float2* __restrict__ ys, int t) {
    int k1 = t & 15, n2 = t >> 4;
    float s1, c1;
    sincosf((float)SIGN * (TWOPI/16.f) * (float)k1, &s1, &c1);
    float2 rb = make_float2(c1, s1);
    float2 w = make_float2(1.f, 0.f);
    float2 acc = make_float2(0.f, 0.f);
    #pragma unroll
    for (int n1 = 0; n1 < 16; ++n1) {
        float2 v = xs[n1*16 + n2];
        acc.x = fmaf(v.x, w.x, fmaf(-v.y, w.y, acc.x));
        acc.y = fmaf(v.x, w.y, fmaf( v.y, w.x, acc.y));
        w = cmulf(w, rb);
    }
    float s2, c2;
    sincosf((float)SIGN * (TWOPI/256.f) * (float)(n2*k1), &s2, &c2);
    ys[t] = cmulf(acc, make_float2(c2, s2));
    __syncthreads();
    float s3, c3;
    sincosf((float)SIGN * (TWOPI/16.f) * (float)n2, &s3, &c3);
    float2 rb2 = make_float2(c3, s3);
    float2 w2 = make_float2(1.f, 0.f);
    float2 acc2 = make_float2(0.f, 0.f);
    #pragma unroll
    for (int m2 = 0; m2 < 16; ++m2) {
        float2 v = ys[m2*16 + k1];
        acc2.x = fmaf(v.x, w2.x, fmaf(-v.y, w2.y, acc2.x));
        acc2.y = fmaf(v.x, w2.y, fmaf( v.y, w2.x, acc2.y));
        w2 = cmulf(w2, rb2);
    }
    return acc2;
}

// ---------------- K1: row rfft (x[b,c,y,:] -> R1[b*C+c][k][y]) ----------------
__global__ __launch_bounds__(256) void k_fft_rows(const float* __restrict__ x,
                                                  float* __restrict__ r1re,
                                                  float* __restrict__ r1im) {
    __shared__ float2 xs[256], ys[256];
    int t = threadIdx.x;
    int bid = blockIdx.x;
    int y = bid & 255;
    int bc = bid >> 8;
    xs[t] = make_float2(x[(size_t)bc*HH*WW + (size_t)y*WW + t], 0.f);
    __syncthreads();
    float2 X = fft256_lds<-1>(xs, ys, t);
    if (t < WF) {
        r1re[((size_t)bc*WF + t)*HH + y] = X.x;
        r1im[((size_t)bc*WF + t)*HH + y] = X.y;
    }
}

// ------------- K2: column fft + amp/pha -------------
__global__ __launch_bounds__(256) void k_fft_cols(const float* __restrict__ r1re,
                                                  const float* __restrict__ r1im,
                                                  float* __restrict__ amp,
                                                  float* __restrict__ pha) {
    __shared__ float2 xs[256], ys[256];
    int t = threadIdx.x;
    int bid = blockIdx.x;
    int k = bid % WF;
    int bc = bid / WF;
    size_t base = ((size_t)bc*WF + k)*HH;
    xs[t] = make_float2(r1re[base + t], r1im[base + t]);
    __syncthreads();
    float2 X = fft256_lds<-1>(xs, ys, t);
    amp[base + t] = sqrtf(X.x*X.x + X.y*X.y);
    pha[base + t] = atan2f(X.y, X.x);
}

// ------------- K_pack: [b,c,k,m] -> channel-innermost [b,k,m,c] -------------
__global__ __launch_bounds__(256) void k_pack(const float* __restrict__ src,
                                              float* __restrict__ dst) {
    __shared__ float tile[64][65];
    int tid = threadIdx.x;
    int bid = blockIdx.x;
    int it = bid & 3;
    int rest = bid >> 2;
    int k = rest % WF;
    int b = rest / WF;
    int i0 = it*64;
    int ii = tid & 63;
    int cg = tid >> 6;
    for (int rep = 0; rep < 16; ++rep) {
        int c = cg*16 + rep;
        tile[c][ii] = src[(size_t)(b*CC + c)*NPIX + (size_t)k*HH + i0 + ii];
    }
    __syncthreads();
    for (int rep = 0; rep < 16; ++rep) {
        int m = cg*16 + rep;
        dst[((size_t)(b*WF + k)*HH + i0 + m)*CC + ii] = tile[ii][m];
    }
}

// ------------- K_wt: wc[oc][c][3][3] -> wct[pos][c][oc] -------------
__global__ void k_wt(const float* __restrict__ wc, float* __restrict__ wct) {
    int idx = blockIdx.x*256 + threadIdx.x;
    if (idx < 9*64*64) {
        int oc = idx & 63;
        int t = idx >> 6;
        int c = t & 63;
        int pos = t >> 6;
        wct[idx] = wc[((size_t)oc*64 + c)*9 + pos];
    }
}

// ------------- K_w0t: w0[oc][c][5][5] -> w0t[c][tap][oc] -------------
__global__ void k_w0t(const float* __restrict__ w0, float* __restrict__ w0t) {
    int idx = blockIdx.x*256 + threadIdx.x;   // 64*25*64 = 102400
    if (idx < 64*25*64) {
        int oc = idx & 63;
        int t = idx >> 6;
        int tap = t % 25;
        int c = t / 25;
        w0t[idx] = w0[((size_t)oc*CC + c)*25 + tap];
    }
}

// ------------- K3: offset conv 3x3 -------------
__global__ __launch_bounds__(256) void k_off_conv(const float* __restrict__ img,
                                                  const float* __restrict__ wp,
                                                  const float* __restrict__ bp,
                                                  float* __restrict__ off) {
    int tid = threadIdx.x;
    int bid = blockIdx.x;
    int j = bid % WF;
    int t = bid / WF;
    int oc = t % 18;
    int b = t / 18;
    float acc = bp[oc];
    for (int c = 0; c < CC; ++c) {
        const float* ib = img + (size_t)(b*CC + c)*NPIX;
        const float* wb = wp + ((size_t)oc*CC + c)*9;
        #pragma unroll
        for (int dj = 0; dj < 3; ++dj) {
            int jj = j + dj - 1;
            if (jj < 0 || jj >= WF) continue;
            const float* col = ib + (size_t)jj*HH;
            #pragma unroll
            for (int di = 0; di < 3; ++di) {
                int ii = tid + di - 1;
                float v = (ii >= 0 && ii < HH) ? col[ii] : 0.f;
                acc += wb[di*3 + dj] * v;
            }
        }
    }
    off[((size_t)(b*18 + oc)*WF + j)*HH + tid] = acc;
}

// ------------- K4: deformable sampling + stride-3 conv, fused -------------
__global__ __launch_bounds__(256) void k_deform(const float* __restrict__ imgc,
                                                const float* __restrict__ off,
                                                const float* __restrict__ wct,
                                                float* __restrict__ out) {
    __shared__ int   cidx[4][144];
    __shared__ float cwgt[4][144];
    __shared__ __align__(16) float S[16*580];
    int tid = threadIdx.x;
    int bid = blockIdx.x;
    int it = bid & 15;
    int rest = bid >> 4;
    int j = rest % WF;
    int b = rest / WF;
    int i0 = it * 16;

    if (tid < 144) {
        int pix = tid / 9;
        int pos = tid % 9;
        int ki = pos / 3, kj = pos % 3;
        int i = i0 + pix;
        int r = 3*i + ki - 1;
        int s = 3*j + kj - 1;
        float g[4] = {0.f,0.f,0.f,0.f};
        int ix[4] = {-1,-1,-1,-1};
        if (r >= 0 && s >= 0) {
            int hq = r/3, nx = r%3;
            int wq = s/3, ny = s%3;
            int n = nx*3 + ny;
            float ox = off[((size_t)(b*18 + n)*WF + wq)*HH + hq];
            float oy = off[((size_t)(b*18 + 9 + n)*WF + wq)*HH + hq];
            float pxf = (float)(hq + nx) + ox;
            float pyf = (float)(wq + ny) + oy;
            float qx = floorf(pxf), qy = floorf(pyf);
            float qltx = fminf(fmaxf(qx, 0.f), 257.f);
            float qlty = fminf(fmaxf(qy, 0.f), 130.f);
            float qrbx = fminf(fmaxf(qx + 1.f, 0.f), 257.f);
            float qrby = fminf(fmaxf(qy + 1.f, 0.f), 130.f);
            float pxc = fminf(fmaxf(pxf, 0.f), 257.f);
            float pyc = fminf(fmaxf(pyf, 0.f), 130.f);
            float glt = (1.f + (qltx - pxc)) * (1.f + (qlty - pyc));
            float grb = (1.f - (qrbx - pxc)) * (1.f - (qrby - pyc));
            float glb = (1.f + (qltx - pxc)) * (1.f - (qrby - pyc));
            float grt = (1.f - (qrbx - pxc)) * (1.f + (qlty - pyc));
            int ax0 = (int)qltx, ax1 = (int)qrbx;
            int ay0 = (int)qlty, ay1 = (int)qrby;
            int cx[4] = {ax0, ax1, ax0, ax1};
            int cy[4] = {ay0, ay1, ay1, ay0};
            g[0]=glt; g[1]=grb; g[2]=glb; g[3]=grt;
            #pragma unroll
            for (int q = 0; q < 4; ++q) {
                int a = cx[q], bq = cy[q];
                ix[q] = (a >= 1 && a <= 256 && bq >= 1 && bq <= 129)
                        ? ((bq-1)*HH + (a-1))*CC : -1;
            }
        }
        #pragma unroll
        for (int q = 0; q < 4; ++q) { cidx[q][tid] = ix[q]; cwgt[q][tid] = g[q]; }
    }
    __syncthreads();

    const float* cb = imgc + (size_t)b * (size_t)WF * HH * CC;
    for (int t = tid; t < 144*64; t += 256) {
        int combo = t >> 6;
        int c = t & 63;
        float sum = 0.f;
        #pragma unroll
        for (int q = 0; q < 4; ++q) {
            int ofs = cidx[q][combo];
            float v = (ofs >= 0) ? cb[(size_t)ofs + c] : 0.f;
            sum += cwgt[q][combo] * v;
        }
        int pix = combo / 9, pos = combo % 9;
        S[pix*580 + pos*64 + c] = sum;
    }
    __syncthreads();

    int pix = tid & 15;
    int oc0 = (tid >> 4) * 4;
    const float* Sp = &S[pix*580];
    float ac[4] = {0.f,0.f,0.f,0.f};
    for (int kk = 0; kk < 576; kk += 4) {
        float4 sv = *(const float4*)&Sp[kk];
        #pragma unroll
        for (int q = 0; q < 4; ++q) {
            float4 wv = *(const float4*)&wct[(size_t)(kk+q)*64 + oc0];
            float sc = (q==0)? sv.x : (q==1)? sv.y : (q==2)? sv.z : sv.w;
            ac[0] += sc*wv.x; ac[1] += sc*wv.y; ac[2] += sc*wv.z; ac[3] += sc*wv.w;
        }
    }
    size_t ob = (size_t)b*CC*NPIX + (size_t)j*HH + i0 + pix;
    #pragma unroll
    for (int q = 0; q < 4; ++q)
        out[ob + (size_t)(oc0+q)*NPIX] = ac[q];
}

// ------------- K5: fused 1x1 convs + trig combine -------------
__global__ __launch_bounds__(256) void k_combine(const float* __restrict__ ampc,
                                                 const float* __restrict__ phac,
                                                 float* __restrict__ a3,
                                                 float* __restrict__ p3,
                                                 const float* __restrict__ w1a,
                                                 const float* __restrict__ b1a,
                                                 const float* __restrict__ w1p,
                                                 const float* __restrict__ b1p) {
    __shared__ float la[64][65], lp[64][65];
    int tid = threadIdx.x;
    int bid = blockIdx.x;
    int quarter = bid & 3;
    int rest = bid >> 2;
    int j = rest % WF;
    int b = rest / WF;
    int i0 = quarter * 64;
    size_t gbase = ((size_t)(b*WF + j)*HH + i0) * CC;
    for (int rep = 0; rep < 16; ++rep) {
        int t = rep*256 + tid;
        int pix = t >> 6;
        int c = t & 63;
        la[c][pix] = ampc[gbase + t];
        lp[c][pix] = phac[gbase + t];
    }
    __syncthreads();
    int ii = tid & 63;
    int wv = tid >> 6;
    float acc_a[16], acc_p[16];
    #pragma unroll
    for (int q = 0; q < 16; ++q) { acc_a[q] = b1a[wv*16+q]; acc_p[q] = b1p[wv*16+q]; }
    for (int c = 0; c < CC; ++c) {
        float av = la[c][ii], pv = lp[c][ii];
        #pragma unroll
        for (int q = 0; q < 16; ++q) {
            acc_a[q] += w1a[(wv*16+q)*CC + c] * av;
            acc_p[q] += w1p[(wv*16+q)*CC + c] * pv;
        }
    }
    #pragma unroll
    for (int q = 0; q < 16; ++q) {
        int oc = wv*16 + q;
        size_t idx = (size_t)(b*CC + oc)*NPIX + (size_t)j*HH + i0 + ii;
        float a3v = a3[idx];
        float p3v = p3[idx];
        float s1, c1, s3, c3;
        sincosf(acc_p[q], &s1, &c1);
        sincosf(p3v, &s3, &c3);
        float re = acc_a[q]*c3 + a3v*c1 + 3e-8f;
        float im = a3v*s1 + acc_a[q]*s3 + 2e-8f;
        a3[idx] = re;
        p3[idx] = im;
    }
}

// ------------- K6: inverse column fft -------------
__global__ __launch_bounds__(256) void k_ifft_cols(const float* __restrict__ ocre,
                                                   const float* __restrict__ ocim,
                                                   float* __restrict__ r2re,
                                                   float* __restrict__ r2im) {
    __shared__ float2 xs[256], ys[256];
    int t = threadIdx.x;
    int bid = blockIdx.x;
    int k = bid % WF;
    int bc = bid / WF;
    size_t base = ((size_t)bc*WF + k)*HH;
    xs[t] = make_float2(ocre[base + t], ocim[base + t]);
    __syncthreads();
    float2 X = fft256_lds<1>(xs, ys, t);
    size_t ob = ((size_t)bc*HH + t)*WF + k;
    r2re[ob] = X.x * (1.0f/256.0f);
    r2im[ob] = X.y * (1.0f/256.0f);
}

// ------------- K7: hermitian row irfft + abs -------------
__global__ __launch_bounds__(256) void k_irfft_rows(const float* __restrict__ r2re,
                                                    const float* __restrict__ r2im,
                                                    float* __restrict__ xr) {
    __shared__ float2 xs[256], ys[256];
    int t = threadIdx.x;
    int bid = blockIdx.x;
    int y = bid & 255;
    int bc = bid >> 8;
    size_t base = ((size_t)bc*HH + y)*WF;
    if (t < WF) xs[t] = make_float2(r2re[base + t], r2im[base + t]);
    __syncthreads();
    if (t >= WF) {
        float2 v = xs[256 - t];
        xs[t] = make_float2(v.x, -v.y);
    }
    __syncthreads();
    float2 X = fft256_lds<1>(xs, ys, t);
    xr[((size_t)bc*HH + y)*WW + t] = fabsf(X.x * (1.0f/256.0f));
}

// ------------- async global->LDS helper (width 16B/lane) -------------
__device__ __forceinline__ void gload_lds16(const float* g, float* l) {
    __builtin_amdgcn_global_load_lds((const __attribute__((address_space(1))) void*)g,
                                     (__attribute__((address_space(3))) void*)l,
                                     16, 0, 0);
}

// ------------- K8: final 5x5 conv, phased staging -------------
// grid = BB*HH*4: q = bid&3 (x-quarter), y = (bid>>2)&255, b = bid>>10.
// lane (tid&63) = oc; wave (tid>>6) covers 16 pixels.
// Restructure vs previous version:
//  - staging coordinates (dy,u,yy,xx,valid,goff,ldsoff) precomputed ONCE (not per channel)
//  - NC=4 channels staged per barrier phase: 32 barriers total instead of 128,
//    and each vmcnt drain is amortized over 1600 wave-FMAs instead of 400
//  - weights for the 4 channels (25.6 KB contiguous in w0t[c][tap][oc]) staged
//    asynchronously via global_load_lds; inner loop reads them with conflict-free
//    ds_read_b32 (lane-consecutive), no per-channel global load-use stall
//  - LDS: lw[6400] + xs[4][5][72] = 31.4 KB, unioned with the 16.6 KB epilogue
//    transpose buffer -> 5 blocks/CU resident (was 3.35)
__global__ __launch_bounds__(256) void k_conv5v(const float* __restrict__ xr,
                                                const float* __restrict__ w0t,
                                                const float* __restrict__ b0,
                                                float* __restrict__ out) {
    __shared__ __align__(16) float smem[7840];   // lw[6400] | xs[4*360]; S[64*65] unions lw
    float* lw  = smem;           // [cc][tap][oc] for 4 channels
    float* xsf = smem + 6400;    // [cc][5][72]

    int tid = threadIdx.x;
    int bid = blockIdx.x;
    int q = bid & 3;
    int y = (bid >> 2) & 255;
    int b = bid >> 10;
    int lane = tid & 63;       // oc
    int wv = tid >> 6;         // pixel sub-group, 16 px each
    int x0 = q * 64;

    // ---- precompute staging slot descriptors (channel-independent) ----
    int tA = tid;                       // slot A: t in [0,256)
    int dyA = tA / 68, uA = tA - dyA*68;
    int yyA = y + dyA - 2, xxA = x0 + uA - 2;
    bool vldA = (yyA >= 0 && yyA < HH && xxA >= 0 && xxA < WW);
    int gA = vldA ? (yyA*WW + xxA) : 0; // clamped: always in-bounds to read
    int lA = dyA*72 + uA;
    int tB = 256 + tid;                 // slot B: t in [256,340)
    bool hasB = (tid < 84);
    int dyB = tB / 68, uB = tB - dyB*68;
    int yyB = y + dyB - 2, xxB = x0 + uB - 2;
    bool vldB = hasB && (yyB >= 0 && yyB < HH && xxB >= 0 && xxB < WW);
    int gB = vldB ? (yyB*WW + xxB) : 0;
    int lB = dyB*72 + uB;

    float bias = b0[lane];
    float acc[16];
    #pragma unroll
    for (int p = 0; p < 16; ++p) acc[p] = bias;

    const float* xbase = xr + ((size_t)(b*CC) << 16);   // HH*WW = 65536

    for (int c0 = 0; c0 < CC; c0 += 4) {
        __syncthreads();   // previous phase's compute done; lw/xs reusable
        // ---- async weight stage: 25600 B contiguous -> lw ----
        {
            const float* wsrc = w0t + (size_t)c0*1600;
            for (int k = wv; k < 25; k += 4)          // wave-uniform
                gload_lds16(wsrc + k*256 + (lane << 2), lw + k*256);
        }
        // ---- pixel stage: 2 predicated loads per thread per channel ----
        #pragma unroll
        for (int cc = 0; cc < 4; ++cc) {
            const float* xb = xbase + ((size_t)(c0 + cc) << 16);
            float fA = xb[gA];
            xsf[cc*360 + lA] = vldA ? fA : 0.f;
            if (hasB) {
                float fB = xb[gB];
                xsf[cc*360 + lB] = vldB ? fB : 0.f;
            }
        }
        __syncthreads();   // drains vmcnt (gl_lds) + lgkm (ds_write)
        // ---- compute 4 channels ----
        #pragma unroll
        for (int cc = 0; cc < 4; ++cc) {
            const float* lwc = lw + cc*1600;
            #pragma unroll
            for (int dy = 0; dy < 5; ++dy) {
                float rv[20];
                const float4* xp = (const float4*)&xsf[cc*360 + dy*72 + wv*16];
                #pragma unroll
                for (int v = 0; v < 5; ++v) {
                    float4 f = xp[v];
                    rv[v*4+0]=f.x; rv[v*4+1]=f.y; rv[v*4+2]=f.z; rv[v*4+3]=f.w;
                }
                #pragma unroll
                for (int dx = 0; dx < 5; ++dx) {
                    float w = lwc[(dy*5 + dx)*64 + lane];   // ds_read_b32, conflict-free
                    #pragma unroll
                    for (int p = 0; p < 16; ++p)
                        acc[p] = fmaf(w, rv[p+dx], acc[p]);
                }
            }
        }
    }
    __syncthreads();
    float (*S)[65] = (float (*)[65])smem;   // union with lw/xs (done with them)
    #pragma unroll
    for (int p = 0; p < 16; ++p) S[lane][wv*16 + p] = acc[p];
    __syncthreads();
    int px = tid & 63;
    #pragma unroll
    for (int rep = 0; rep < 16; ++rep) {
        int oc = wv*16 + rep;
        out[((size_t)(b*CC + oc)*HH + y)*WW + x0 + px] = S[oc][px];
    }
}

extern "C" void kernel_launch(void* const* d_in, const int* in_sizes, int n_in,
                              void* d_out, int out_size, void* d_ws, size_t ws_size,
                              hipStream_t stream) {
    const float* x    = (const float*)d_in[0];
    const float* wp_a = (const float*)d_in[1];
    const float* bp_a = (const float*)d_in[2];
    const float* wc_a = (const float*)d_in[3];
    const float* w1_a = (const float*)d_in[4];
    const float* b1_a = (const float*)d_in[5];
    const float* wp_p = (const float*)d_in[6];
    const float* bp_p = (const float*)d_in[7];
    const float* wc_p = (const float*)d_in[8];
    const float* w1_p = (const float*)d_in[9];
    const float* b1_p = (const float*)d_in[10];
    const float* w0   = (const float*)d_in[11];
    const float* b0   = (const float*)d_in[12];
    float* out = (float*)d_out;
    float* ws  = (float*)d_ws;

    // Workspace map (floats). Peak = 4*NS + off/wct/w0t ≈ 155 MB.
    float* R0 = ws;
    float* R1 = ws + 2*NS;
    float* R2 = ws + 4*NS;

    float* r1re = R0;
    float* r1im = R0 + NS;
    float* amp  = R1;
    float* pha  = R1 + NS;
    float* ampc = R0;
    float* phac = R0 + NS;
    size_t offsz = (size_t)BB*18*NPIX;
    float* offa = R2;
    float* offp = R2 + offsz;
    float* wcta = R2 + 2*offsz;
    float* wctp = wcta + 9*64*64;
    float* w0tp = wctp + 9*64*64;      // 64*25*64 = 102400 floats
    float* A3   = R1;
    float* P3   = R1 + NS;
    float* r2re = R0;
    float* r2im = R0 + NS;
    float* xrp  = R1;

    k_wt<<<144, 256, 0, stream>>>(wc_a, wcta);
    k_wt<<<144, 256, 0, stream>>>(wc_p, wctp);
    k_w0t<<<400, 256, 0, stream>>>(w0, w0tp);
    k_fft_rows<<<BB*CC*HH, 256, 0, stream>>>(x, r1re, r1im);
    k_fft_cols<<<BB*CC*WF, 256, 0, stream>>>(r1re, r1im, amp, pha);
    k_pack<<<BB*WF*4, 256, 0, stream>>>(amp, ampc);
    k_pack<<<BB*WF*4, 256, 0, stream>>>(pha, phac);
    k_off_conv<<<BB*18*WF, 256, 0, stream>>>(amp, wp_a, bp_a, offa);
    k_off_conv<<<BB*18*WF, 256, 0, stream>>>(pha, wp_p, bp_p, offp);
    k_deform<<<BB*WF*16, 256, 0, stream>>>(ampc, offa, wcta, A3);
    k_deform<<<BB*WF*16, 256, 0, stream>>>(phac, offp, wctp, P3);
    k_combine<<<BB*WF*4, 256, 0, stream>>>(ampc, phac, A3, P3, w1_a, b1_a, w1_p, b1_p);
    k_ifft_cols<<<BB*CC*WF, 256, 0, stream>>>(A3, P3, r2re, r2im);
    k_irfft_rows<<<BB*CC*HH, 256, 0, stream>>>(r2re, r2im, xrp);
    k_conv5v<<<BB*HH*4, 256, 0, stream>>>(xrp, w0tp, b0, out);
}

// Round 2
// 2971.617 us; speedup vs baseline: 1.1836x; 1.1836x over previous
//
#include <hip/hip_runtime.h>
#include <math.h>

#define BB 4
#define CC 64
#define HH 256
#define WW 256
#define WF 129
#define NPIX (WF*HH)                 // 33024
#define NS ((size_t)BB*CC*NPIX)      // 8454144 floats per plane-set
#define TWOPI 6.283185307179586f

typedef __attribute__((ext_vector_type(8))) short short8v;
typedef __attribute__((ext_vector_type(4))) float float4v;

// ---------------- four-step 256-point complex FFT in LDS ----------------
__device__ __forceinline__ float2 cmulf(float2 a, float2 b) {
    return make_float2(a.x*b.x - a.y*b.y, a.x*b.y + a.y*b.x);
}

template<int SIGN>
__device__ __forceinline__ float2 fft256_lds(const float2* __restrict__ xs,
                                             float2* __restrict__ ys, int t) {
    int k1 = t & 15, n2 = t >> 4;
    float s1, c1;
    sincosf((float)SIGN * (TWOPI/16.f) * (float)k1, &s1, &c1);
    float2 rb = make_float2(c1, s1);
    float2 w = make_float2(1.f, 0.f);
    float2 acc = make_float2(0.f, 0.f);
    #pragma unroll
    for (int n1 = 0; n1 < 16; ++n1) {
        float2 v = xs[n1*16 + n2];
        acc.x = fmaf(v.x, w.x, fmaf(-v.y, w.y, acc.x));
        acc.y = fmaf(v.x, w.y, fmaf( v.y, w.x, acc.y));
        w = cmulf(w, rb);
    }
    float s2, c2;
    sincosf((float)SIGN * (TWOPI/256.f) * (float)(n2*k1), &s2, &c2);
    ys[t] = cmulf(acc, make_float2(c2, s2));
    __syncthreads();
    float s3, c3;
    sincosf((float)SIGN * (TWOPI/16.f) * (float)n2, &s3, &c3);
    float2 rb2 = make_float2(c3, s3);
    float2 w2 = make_float2(1.f, 0.f);
    float2 acc2 = make_float2(0.f, 0.f);
    #pragma unroll
    for (int m2 = 0; m2 < 16; ++m2) {
        float2 v = ys[m2*16 + k1];
        acc2.x = fmaf(v.x, w2.x, fmaf(-v.y, w2.y, acc2.x));
        acc2.y = fmaf(v.x, w2.y, fmaf( v.y, w2.x, acc2.y));
        w2 = cmulf(w2, rb2);
    }
    return acc2;
}

// ---------------- K1: row rfft ----------------
__global__ __launch_bounds__(256) void k_fft_rows(const float* __restrict__ x,
                                                  float* __restrict__ r1re,
                                                  float* __restrict__ r1im) {
    __shared__ float2 xs[256], ys[256];
    int t = threadIdx.x;
    int bid = blockIdx.x;
    int y = bid & 255;
    int bc = bid >> 8;
    xs[t] = make_float2(x[(size_t)bc*HH*WW + (size_t)y*WW + t], 0.f);
    __syncthreads();
    float2 X = fft256_lds<-1>(xs, ys, t);
    if (t < WF) {
        r1re[((size_t)bc*WF + t)*HH + y] = X.x;
        r1im[((size_t)bc*WF + t)*HH + y] = X.y;
    }
}

// ------------- K2: column fft + amp/pha -------------
__global__ __launch_bounds__(256) void k_fft_cols(const float* __restrict__ r1re,
                                                  const float* __restrict__ r1im,
                                                  float* __restrict__ amp,
                                                  float* __restrict__ pha) {
    __shared__ float2 xs[256], ys[256];
    int t = threadIdx.x;
    int bid = blockIdx.x;
    int k = bid % WF;
    int bc = bid / WF;
    size_t base = ((size_t)bc*WF + k)*HH;
    xs[t] = make_float2(r1re[base + t], r1im[base + t]);
    __syncthreads();
    float2 X = fft256_lds<-1>(xs, ys, t);
    amp[base + t] = sqrtf(X.x*X.x + X.y*X.y);
    pha[base + t] = atan2f(X.y, X.x);
}

// ------------- K_pack: [b,c,k,m] -> channel-innermost [b,k,m,c] -------------
__global__ __launch_bounds__(256) void k_pack(const float* __restrict__ src,
                                              float* __restrict__ dst) {
    __shared__ float tile[64][65];
    int tid = threadIdx.x;
    int bid = blockIdx.x;
    int it = bid & 3;
    int rest = bid >> 2;
    int k = rest % WF;
    int b = rest / WF;
    int i0 = it*64;
    int ii = tid & 63;
    int cg = tid >> 6;
    for (int rep = 0; rep < 16; ++rep) {
        int c = cg*16 + rep;
        tile[c][ii] = src[(size_t)(b*CC + c)*NPIX + (size_t)k*HH + i0 + ii];
    }
    __syncthreads();
    for (int rep = 0; rep < 16; ++rep) {
        int m = cg*16 + rep;
        dst[((size_t)(b*WF + k)*HH + i0 + m)*CC + ii] = tile[ii][m];
    }
}

// ------------- K_wt: wc[oc][c][3][3] -> wct[pos][c][oc] -------------
__global__ void k_wt(const float* __restrict__ wc, float* __restrict__ wct) {
    int idx = blockIdx.x*256 + threadIdx.x;
    if (idx < 9*64*64) {
        int oc = idx & 63;
        int t = idx >> 6;
        int c = t & 63;
        int pos = t >> 6;
        wct[idx] = wc[((size_t)oc*64 + c)*9 + pos];
    }
}

// ------------- bf16 helpers -------------
__device__ __forceinline__ unsigned short bf16r(float f) {
    unsigned u = __float_as_uint(f);
    unsigned r = (u + 0x7FFFu + ((u >> 16) & 1u)) >> 16;
    return (unsigned short)r;
}
__device__ __forceinline__ float bf16f(unsigned short h) {
    return __uint_as_float(((unsigned)h) << 16);
}

// ------------- K_wsplit: w0[oc][c][5][5] -> whT/wlT [tap][oc][c] bf16 split ----
__global__ void k_wsplit(const float* __restrict__ w0,
                         unsigned short* __restrict__ whT,
                         unsigned short* __restrict__ wlT) {
    int idx = blockIdx.x*256 + threadIdx.x;   // 25*64*64 = 102400
    if (idx < 25*64*64) {
        int c = idx & 63;
        int t = idx >> 6;
        int oc = t & 63;
        int tap = t >> 6;
        float v = w0[((size_t)oc*CC + c)*25 + tap];
        unsigned short h = bf16r(v);
        float l = v - bf16f(h);
        whT[idx] = h;
        wlT[idx] = bf16r(l);
    }
}

// ------------- K3: offset conv 3x3 -------------
__global__ __launch_bounds__(256) void k_off_conv(const float* __restrict__ img,
                                                  const float* __restrict__ wp,
                                                  const float* __restrict__ bp,
                                                  float* __restrict__ off) {
    int tid = threadIdx.x;
    int bid = blockIdx.x;
    int j = bid % WF;
    int t = bid / WF;
    int oc = t % 18;
    int b = t / 18;
    float acc = bp[oc];
    for (int c = 0; c < CC; ++c) {
        const float* ib = img + (size_t)(b*CC + c)*NPIX;
        const float* wb = wp + ((size_t)oc*CC + c)*9;
        #pragma unroll
        for (int dj = 0; dj < 3; ++dj) {
            int jj = j + dj - 1;
            if (jj < 0 || jj >= WF) continue;
            const float* col = ib + (size_t)jj*HH;
            #pragma unroll
            for (int di = 0; di < 3; ++di) {
                int ii = tid + di - 1;
                float v = (ii >= 0 && ii < HH) ? col[ii] : 0.f;
                acc += wb[di*3 + dj] * v;
            }
        }
    }
    off[((size_t)(b*18 + oc)*WF + j)*HH + tid] = acc;
}

// ------------- K4: deformable sampling + stride-3 conv, fused -------------
__global__ __launch_bounds__(256) void k_deform(const float* __restrict__ imgc,
                                                const float* __restrict__ off,
                                                const float* __restrict__ wct,
                                                float* __restrict__ out) {
    __shared__ int   cidx[4][144];
    __shared__ float cwgt[4][144];
    __shared__ __align__(16) float S[16*580];
    int tid = threadIdx.x;
    int bid = blockIdx.x;
    int it = bid & 15;
    int rest = bid >> 4;
    int j = rest % WF;
    int b = rest / WF;
    int i0 = it * 16;

    if (tid < 144) {
        int pix = tid / 9;
        int pos = tid % 9;
        int ki = pos / 3, kj = pos % 3;
        int i = i0 + pix;
        int r = 3*i + ki - 1;
        int s = 3*j + kj - 1;
        float g[4] = {0.f,0.f,0.f,0.f};
        int ix[4] = {-1,-1,-1,-1};
        if (r >= 0 && s >= 0) {
            int hq = r/3, nx = r%3;
            int wq = s/3, ny = s%3;
            int n = nx*3 + ny;
            float ox = off[((size_t)(b*18 + n)*WF + wq)*HH + hq];
            float oy = off[((size_t)(b*18 + 9 + n)*WF + wq)*HH + hq];
            float pxf = (float)(hq + nx) + ox;
            float pyf = (float)(wq + ny) + oy;
            float qx = floorf(pxf), qy = floorf(pyf);
            float qltx = fminf(fmaxf(qx, 0.f), 257.f);
            float qlty = fminf(fmaxf(qy, 0.f), 130.f);
            float qrbx = fminf(fmaxf(qx + 1.f, 0.f), 257.f);
            float qrby = fminf(fmaxf(qy + 1.f, 0.f), 130.f);
            float pxc = fminf(fmaxf(pxf, 0.f), 257.f);
            float pyc = fminf(fmaxf(pyf, 0.f), 130.f);
            float glt = (1.f + (qltx - pxc)) * (1.f + (qlty - pyc));
            float grb = (1.f - (qrbx - pxc)) * (1.f - (qrby - pyc));
            float glb = (1.f + (qltx - pxc)) * (1.f - (qrby - pyc));
            float grt = (1.f - (qrbx - pxc)) * (1.f + (qlty - pyc));
            int ax0 = (int)qltx, ax1 = (int)qrbx;
            int ay0 = (int)qlty, ay1 = (int)qrby;
            int cx[4] = {ax0, ax1, ax0, ax1};
            int cy[4] = {ay0, ay1, ay1, ay0};
            g[0]=glt; g[1]=grb; g[2]=glb; g[3]=grt;
            #pragma unroll
            for (int q = 0; q < 4; ++q) {
                int a = cx[q], bq = cy[q];
                ix[q] = (a >= 1 && a <= 256 && bq >= 1 && bq <= 129)
                        ? ((bq-1)*HH + (a-1))*CC : -1;
            }
        }
        #pragma unroll
        for (int q = 0; q < 4; ++q) { cidx[q][tid] = ix[q]; cwgt[q][tid] = g[q]; }
    }
    __syncthreads();

    const float* cb = imgc + (size_t)b * (size_t)WF * HH * CC;
    for (int t = tid; t < 144*64; t += 256) {
        int combo = t >> 6;
        int c = t & 63;
        float sum = 0.f;
        #pragma unroll
        for (int q = 0; q < 4; ++q) {
            int ofs = cidx[q][combo];
            float v = (ofs >= 0) ? cb[(size_t)ofs + c] : 0.f;
            sum += cwgt[q][combo] * v;
        }
        int pix = combo / 9, pos = combo % 9;
        S[pix*580 + pos*64 + c] = sum;
    }
    __syncthreads();

    int pix = tid & 15;
    int oc0 = (tid >> 4) * 4;
    const float* Sp = &S[pix*580];
    float ac[4] = {0.f,0.f,0.f,0.f};
    for (int kk = 0; kk < 576; kk += 4) {
        float4 sv = *(const float4*)&Sp[kk];
        #pragma unroll
        for (int q = 0; q < 4; ++q) {
            float4 wv = *(const float4*)&wct[(size_t)(kk+q)*64 + oc0];
            float sc = (q==0)? sv.x : (q==1)? sv.y : (q==2)? sv.z : sv.w;
            ac[0] += sc*wv.x; ac[1] += sc*wv.y; ac[2] += sc*wv.z; ac[3] += sc*wv.w;
        }
    }
    size_t ob = (size_t)b*CC*NPIX + (size_t)j*HH + i0 + pix;
    #pragma unroll
    for (int q = 0; q < 4; ++q)
        out[ob + (size_t)(oc0+q)*NPIX] = ac[q];
}

// ------------- K5: fused 1x1 convs + trig combine -------------
__global__ __launch_bounds__(256) void k_combine(const float* __restrict__ ampc,
                                                 const float* __restrict__ phac,
                                                 float* __restrict__ a3,
                                                 float* __restrict__ p3,
                                                 const float* __restrict__ w1a,
                                                 const float* __restrict__ b1a,
                                                 const float* __restrict__ w1p,
                                                 const float* __restrict__ b1p) {
    __shared__ float la[64][65], lp[64][65];
    int tid = threadIdx.x;
    int bid = blockIdx.x;
    int quarter = bid & 3;
    int rest = bid >> 2;
    int j = rest % WF;
    int b = rest / WF;
    int i0 = quarter * 64;
    size_t gbase = ((size_t)(b*WF + j)*HH + i0) * CC;
    for (int rep = 0; rep < 16; ++rep) {
        int t = rep*256 + tid;
        int pix = t >> 6;
        int c = t & 63;
        la[c][pix] = ampc[gbase + t];
        lp[c][pix] = phac[gbase + t];
    }
    __syncthreads();
    int ii = tid & 63;
    int wv = tid >> 6;
    float acc_a[16], acc_p[16];
    #pragma unroll
    for (int q = 0; q < 16; ++q) { acc_a[q] = b1a[wv*16+q]; acc_p[q] = b1p[wv*16+q]; }
    for (int c = 0; c < CC; ++c) {
        float av = la[c][ii], pv = lp[c][ii];
        #pragma unroll
        for (int q = 0; q < 16; ++q) {
            acc_a[q] += w1a[(wv*16+q)*CC + c] * av;
            acc_p[q] += w1p[(wv*16+q)*CC + c] * pv;
        }
    }
    #pragma unroll
    for (int q = 0; q < 16; ++q) {
        int oc = wv*16 + q;
        size_t idx = (size_t)(b*CC + oc)*NPIX + (size_t)j*HH + i0 + ii;
        float a3v = a3[idx];
        float p3v = p3[idx];
        float s1, c1, s3, c3;
        sincosf(acc_p[q], &s1, &c1);
        sincosf(p3v, &s3, &c3);
        float re = acc_a[q]*c3 + a3v*c1 + 3e-8f;
        float im = a3v*s1 + acc_a[q]*s3 + 2e-8f;
        a3[idx] = re;
        p3[idx] = im;
    }
}

// ------------- K6: inverse column fft -------------
__global__ __launch_bounds__(256) void k_ifft_cols(const float* __restrict__ ocre,
                                                   const float* __restrict__ ocim,
                                                   float* __restrict__ r2re,
                                                   float* __restrict__ r2im) {
    __shared__ float2 xs[256], ys[256];
    int t = threadIdx.x;
    int bid = blockIdx.x;
    int k = bid % WF;
    int bc = bid / WF;
    size_t base = ((size_t)bc*WF + k)*HH;
    xs[t] = make_float2(ocre[base + t], ocim[base + t]);
    __syncthreads();
    float2 X = fft256_lds<1>(xs, ys, t);
    size_t ob = ((size_t)bc*HH + t)*WF + k;
    r2re[ob] = X.x * (1.0f/256.0f);
    r2im[ob] = X.y * (1.0f/256.0f);
}

// ------------- K7: hermitian row irfft + abs -------------
__global__ __launch_bounds__(256) void k_irfft_rows(const float* __restrict__ r2re,
                                                    const float* __restrict__ r2im,
                                                    float* __restrict__ xr) {
    __shared__ float2 xs[256], ys[256];
    int t = threadIdx.x;
    int bid = blockIdx.x;
    int y = bid & 255;
    int bc = bid >> 8;
    size_t base = ((size_t)bc*HH + y)*WF;
    if (t < WF) xs[t] = make_float2(r2re[base + t], r2im[base + t]);
    __syncthreads();
    if (t >= WF) {
        float2 v = xs[256 - t];
        xs[t] = make_float2(v.x, -v.y);
    }
    __syncthreads();
    float2 X = fft256_lds<1>(xs, ys, t);
    xr[((size_t)bc*HH + y)*WW + t] = fabsf(X.x * (1.0f/256.0f));
}

// ------------- K_split: xr[b][c][y][x] fp32 -> xh/xl [b][ch][y][x][32c] bf16 ---
// grid = BB*HH*4 (b, y, x-quarter); LDS transpose tile 64c x 64x.
__global__ __launch_bounds__(256) void k_split(const float* __restrict__ xr,
                                               unsigned short* __restrict__ xh,
                                               unsigned short* __restrict__ xl) {
    __shared__ float tile[64][65];
    int tid = threadIdx.x;
    int bid = blockIdx.x;
    int q = bid & 3;
    int y = (bid >> 2) & 255;
    int b = bid >> 10;
    int x0 = q*64;
    int lane = tid & 63;
    int cg = tid >> 6;
    for (int rep = 0; rep < 16; ++rep) {
        int c = cg*16 + rep;
        tile[c][lane] = xr[(((size_t)(b*CC + c)*HH + y)*WW) + x0 + lane];
    }
    __syncthreads();
    int x = tid >> 2;
    int c0 = (tid & 3)*8;
    #pragma unroll
    for (int ch = 0; ch < 2; ++ch) {
        short8v hv, lv;
        #pragma unroll
        for (int j = 0; j < 8; ++j) {
            float v = tile[ch*32 + c0 + j][x];
            unsigned short h = bf16r(v);
            float l = v - bf16f(h);
            hv[j] = (short)h;
            lv[j] = (short)bf16r(l);
        }
        size_t ob = ((((size_t)(b*2 + ch)*HH + y)*WW) + x0 + x)*32 + c0;
        *(short8v*)&xh[ob] = hv;
        *(short8v*)&xl[ob] = lv;
    }
}

// ------------- K8: final 5x5 conv via split-bf16 MFMA -------------
// block: 2 output rows x 64 px x 64 oc.  grid = BB * 128 * 4.
// LDS image tile: [plane h/l][6 rows][72 x][40c-pad] bf16 = 69120 B.
// 3-pass split: acc += Ah*Bh + Ah*Bl + Al*Bh  (xl*wl term ~2^-18, dropped).
// wave w: row = w>>1, oc-half = (w&1)*32 -> 2 octiles x 4 pxtiles of 16x16.
#define LROW 40
#define LX 72
#define LROWS 6
#define PLANE (LROWS*LX*LROW)    // 17280 ushorts

__global__ __launch_bounds__(256) void k_conv5m(const unsigned short* __restrict__ xh,
                                                const unsigned short* __restrict__ xl,
                                                const unsigned short* __restrict__ whT,
                                                const unsigned short* __restrict__ wlT,
                                                const float* __restrict__ b0,
                                                float* __restrict__ out) {
    __shared__ unsigned short smem[2*PLANE];
    int tid = threadIdx.x;
    int bid = blockIdx.x;
    int q = bid & 3;
    int yb = (bid >> 2) & 127;
    int b = bid >> 9;
    int x0 = q*64;
    int y0 = yb*2;
    int lane = tid & 63;
    int w = tid >> 6;
    int wrow = w >> 1;          // output row within block (0..1)
    int oc0 = (w & 1)*32;       // oc half for this wave
    int l15 = lane & 15;
    int l4  = lane >> 4;

    // bias-initialized accumulators: acc[octile][pxtile][reg]
    float4v acc[2][4];
    #pragma unroll
    for (int o = 0; o < 2; ++o) {
        float4v bi;
        #pragma unroll
        for (int r = 0; r < 4; ++r) bi[r] = b0[oc0 + o*16 + l4*4 + r];
        #pragma unroll
        for (int p = 0; p < 4; ++p) acc[o][p] = bi;
    }

    for (int ch = 0; ch < 2; ++ch) {
        __syncthreads();
        // ---- stage image tile for this channel-half (both planes) ----
        #pragma unroll
        for (int plane = 0; plane < 2; ++plane) {
            const unsigned short* src = plane ? xl : xh;
            size_t gb = ((size_t)(b*2 + ch)*HH);
            for (int it = tid; it < LROWS*LX*4; it += 256) {   // 1728
                int part = it & 3;
                int s = it >> 2;
                int row = s / LX;
                int xi = s - row*LX;
                int gy = y0 + row - 2;
                int gx = x0 + xi - 2;
                short8v v = {0,0,0,0,0,0,0,0};
                if (gy >= 0 && gy < HH && gx >= 0 && gx < WW)
                    v = *(const short8v*)&src[((gb + gy)*WW + gx)*32 + part*8];
                *(short8v*)&smem[plane*PLANE + (row*LX + xi)*LROW + part*8] = v;
            }
        }
        __syncthreads();
        // ---- 25 taps, K=32 channels each, 3-pass MFMA ----
        for (int tap = 0; tap < 25; ++tap) {
            int dy = tap/5, dx = tap - dy*5;
            // A fragments: whT/wlT[tap][oc][c]; lane: oc = base + l15, k = l4*8+j
            size_t wb = ((size_t)tap*64 + oc0 + l15)*64 + ch*32 + l4*8;
            short8v Ah0 = *(const short8v*)&whT[wb];
            short8v Ah1 = *(const short8v*)&whT[wb + 16*64];
            short8v Al0 = *(const short8v*)&wlT[wb];
            short8v Al1 = *(const short8v*)&wlT[wb + 16*64];
            // B fragments from LDS: x-slot = p*16 + l15 + dx, row-slot = wrow+dy
            int rbase = (wrow + dy)*LX + l15 + dx;
            short8v Bh[4], Bl[4];
            #pragma unroll
            for (int p = 0; p < 4; ++p) {
                int a = (rbase + p*16)*LROW + l4*8;
                Bh[p] = *(const short8v*)&smem[a];
                Bl[p] = *(const short8v*)&smem[a + PLANE];
            }
            #pragma unroll
            for (int o = 0; o < 2; ++o) {
                short8v Ah = o ? Ah1 : Ah0;
                short8v Al = o ? Al1 : Al0;
                #pragma unroll
                for (int p = 0; p < 4; ++p) {
                    acc[o][p] = __builtin_amdgcn_mfma_f32_16x16x32_bf16(Ah, Bh[p], acc[o][p], 0, 0, 0);
                    acc[o][p] = __builtin_amdgcn_mfma_f32_16x16x32_bf16(Ah, Bl[p], acc[o][p], 0, 0, 0);
                    acc[o][p] = __builtin_amdgcn_mfma_f32_16x16x32_bf16(Al, Bh[p], acc[o][p], 0, 0, 0);
                }
            }
        }
    }

    // ---- epilogue: D[m=oc within tile][n=px]; col = l15, row = l4*4+r ----
    int y = y0 + wrow;
    #pragma unroll
    for (int o = 0; o < 2; ++o) {
        #pragma unroll
        for (int p = 0; p < 4; ++p) {
            #pragma unroll
            for (int r = 0; r < 4; ++r) {
                int oc = oc0 + o*16 + l4*4 + r;
                int x = x0 + p*16 + l15;
                out[(((size_t)(b*CC + oc)*HH + y)*WW) + x] = acc[o][p][r];
            }
        }
    }
}

extern "C" void kernel_launch(void* const* d_in, const int* in_sizes, int n_in,
                              void* d_out, int out_size, void* d_ws, size_t ws_size,
                              hipStream_t stream) {
    const float* x    = (const float*)d_in[0];
    const float* wp_a = (const float*)d_in[1];
    const float* bp_a = (const float*)d_in[2];
    const float* wc_a = (const float*)d_in[3];
    const float* w1_a = (const float*)d_in[4];
    const float* b1_a = (const float*)d_in[5];
    const float* wp_p = (const float*)d_in[6];
    const float* bp_p = (const float*)d_in[7];
    const float* wc_p = (const float*)d_in[8];
    const float* w1_p = (const float*)d_in[9];
    const float* b1_p = (const float*)d_in[10];
    const float* w0   = (const float*)d_in[11];
    const float* b0   = (const float*)d_in[12];
    float* out = (float*)d_out;
    float* ws  = (float*)d_ws;

    // Workspace map (floats). Peak = 4*NS + off/wct/w0split ≈ 155 MB.
    float* R0 = ws;
    float* R1 = ws + 2*NS;
    float* R2 = ws + 4*NS;

    float* r1re = R0;
    float* r1im = R0 + NS;
    float* amp  = R1;
    float* pha  = R1 + NS;
    float* ampc = R0;
    float* phac = R0 + NS;
    size_t offsz = (size_t)BB*18*NPIX;
    float* offa = R2;
    float* offp = R2 + offsz;
    float* wcta = R2 + 2*offsz;
    float* wctp = wcta + 9*64*64;
    // split weights reuse the old w0t region (102400 floats = 204800 ushorts)
    unsigned short* whT = (unsigned short*)(wctp + 9*64*64);
    unsigned short* wlT = whT + 25*64*64;
    float* A3   = R1;
    float* P3   = R1 + NS;
    float* r2re = R0;
    float* r2im = R0 + NS;
    float* xrp  = R1;
    // split image planes live in R0 (r2re/r2im dead after k_irfft_rows)
    // each plane: 4*2*256*256*32 = 16777216 ushorts = 8388608 floats; 2 planes = 2*NS - small slack
    unsigned short* xhp = (unsigned short*)R0;
    unsigned short* xlp = xhp + (size_t)BB*2*HH*WW*32;

    k_wt<<<144, 256, 0, stream>>>(wc_a, wcta);
    k_wt<<<144, 256, 0, stream>>>(wc_p, wctp);
    k_wsplit<<<400, 256, 0, stream>>>(w0, whT, wlT);
    k_fft_rows<<<BB*CC*HH, 256, 0, stream>>>(x, r1re, r1im);
    k_fft_cols<<<BB*CC*WF, 256, 0, stream>>>(r1re, r1im, amp, pha);
    k_pack<<<BB*WF*4, 256, 0, stream>>>(amp, ampc);
    k_pack<<<BB*WF*4, 256, 0, stream>>>(pha, phac);
    k_off_conv<<<BB*18*WF, 256, 0, stream>>>(amp, wp_a, bp_a, offa);
    k_off_conv<<<BB*18*WF, 256, 0, stream>>>(pha, wp_p, bp_p, offp);
    k_deform<<<BB*WF*16, 256, 0, stream>>>(ampc, offa, wcta, A3);
    k_deform<<<BB*WF*16, 256, 0, stream>>>(phac, offp, wctp, P3);
    k_combine<<<BB*WF*4, 256, 0, stream>>>(ampc, phac, A3, P3, w1_a, b1_a, w1_p, b1_p);
    k_ifft_cols<<<BB*CC*WF, 256, 0, stream>>>(A3, P3, r2re, r2im);
    k_irfft_rows<<<BB*CC*HH, 256, 0, stream>>>(r2re, r2im, xrp);
    k_split<<<BB*HH*4, 256, 0, stream>>>(xrp, xhp, xlp);
    k_conv5m<<<BB*128*4, 256, 0, stream>>>(xhp, xlp, whT, wlT, b0, out);
}

// Round 3
// 2151.076 us; speedup vs baseline: 1.6351x; 1.3815x over previous
//
#include <hip/hip_runtime.h>
#include <math.h>

#define BB 4
#define CC 64
#define HH 256
#define WW 256
#define WF 129
#define NPIX (WF*HH)                 // 33024
#define NS ((size_t)BB*CC*NPIX)      // 8454144 floats per plane-set
#define TWOPI 6.283185307179586f

typedef __attribute__((ext_vector_type(8))) short short8v;
typedef __attribute__((ext_vector_type(4))) float float4v;

// ---------------- four-step 256-point complex FFT in LDS ----------------
__device__ __forceinline__ float2 cmulf(float2 a, float2 b) {
    return make_float2(a.x*b.x - a.y*b.y, a.x*b.y + a.y*b.x);
}

template<int SIGN>
__device__ __forceinline__ float2 fft256_lds(const float2* __restrict__ xs,
                                             float2* __restrict__ ys, int t) {
    int k1 = t & 15, n2 = t >> 4;
    float s1, c1;
    sincosf((float)SIGN * (TWOPI/16.f) * (float)k1, &s1, &c1);
    float2 rb = make_float2(c1, s1);
    float2 w = make_float2(1.f, 0.f);
    float2 acc = make_float2(0.f, 0.f);
    #pragma unroll
    for (int n1 = 0; n1 < 16; ++n1) {
        float2 v = xs[n1*16 + n2];
        acc.x = fmaf(v.x, w.x, fmaf(-v.y, w.y, acc.x));
        acc.y = fmaf(v.x, w.y, fmaf( v.y, w.x, acc.y));
        w = cmulf(w, rb);
    }
    float s2, c2;
    sincosf((float)SIGN * (TWOPI/256.f) * (float)(n2*k1), &s2, &c2);
    ys[t] = cmulf(acc, make_float2(c2, s2));
    __syncthreads();
    float s3, c3;
    sincosf((float)SIGN * (TWOPI/16.f) * (float)n2, &s3, &c3);
    float2 rb2 = make_float2(c3, s3);
    float2 w2 = make_float2(1.f, 0.f);
    float2 acc2 = make_float2(0.f, 0.f);
    #pragma unroll
    for (int m2 = 0; m2 < 16; ++m2) {
        float2 v = ys[m2*16 + k1];
        acc2.x = fmaf(v.x, w2.x, fmaf(-v.y, w2.y, acc2.x));
        acc2.y = fmaf(v.x, w2.y, fmaf( v.y, w2.x, acc2.y));
        w2 = cmulf(w2, rb2);
    }
    return acc2;
}

// ---------------- K1: row rfft ----------------
__global__ __launch_bounds__(256) void k_fft_rows(const float* __restrict__ x,
                                                  float* __restrict__ r1re,
                                                  float* __restrict__ r1im) {
    __shared__ float2 xs[256], ys[256];
    int t = threadIdx.x;
    int bid = blockIdx.x;
    int y = bid & 255;
    int bc = bid >> 8;
    xs[t] = make_float2(x[(size_t)bc*HH*WW + (size_t)y*WW + t], 0.f);
    __syncthreads();
    float2 X = fft256_lds<-1>(xs, ys, t);
    if (t < WF) {
        r1re[((size_t)bc*WF + t)*HH + y] = X.x;
        r1im[((size_t)bc*WF + t)*HH + y] = X.y;
    }
}

// ------------- K2: column fft + amp/pha -------------
__global__ __launch_bounds__(256) void k_fft_cols(const float* __restrict__ r1re,
                                                  const float* __restrict__ r1im,
                                                  float* __restrict__ amp,
                                                  float* __restrict__ pha) {
    __shared__ float2 xs[256], ys[256];
    int t = threadIdx.x;
    int bid = blockIdx.x;
    int k = bid % WF;
    int bc = bid / WF;
    size_t base = ((size_t)bc*WF + k)*HH;
    xs[t] = make_float2(r1re[base + t], r1im[base + t]);
    __syncthreads();
    float2 X = fft256_lds<-1>(xs, ys, t);
    amp[base + t] = sqrtf(X.x*X.x + X.y*X.y);
    pha[base + t] = atan2f(X.y, X.x);
}

// ------------- K_pack: [b,c,k,m] -> channel-innermost [b,k,m,c] -------------
__global__ __launch_bounds__(256) void k_pack(const float* __restrict__ src,
                                              float* __restrict__ dst) {
    __shared__ float tile[64][65];
    int tid = threadIdx.x;
    int bid = blockIdx.x;
    int it = bid & 3;
    int rest = bid >> 2;
    int k = rest % WF;
    int b = rest / WF;
    int i0 = it*64;
    int ii = tid & 63;
    int cg = tid >> 6;
    for (int rep = 0; rep < 16; ++rep) {
        int c = cg*16 + rep;
        tile[c][ii] = src[(size_t)(b*CC + c)*NPIX + (size_t)k*HH + i0 + ii];
    }
    __syncthreads();
    for (int rep = 0; rep < 16; ++rep) {
        int m = cg*16 + rep;
        dst[((size_t)(b*WF + k)*HH + i0 + m)*CC + ii] = tile[ii][m];
    }
}

// ------------- bf16 helpers -------------
__device__ __forceinline__ unsigned short bf16r(float f) {
    unsigned u = __float_as_uint(f);
    unsigned r = (u + 0x7FFFu + ((u >> 16) & 1u)) >> 16;
    return (unsigned short)r;
}
__device__ __forceinline__ float bf16f(unsigned short h) {
    return __uint_as_float(((unsigned)h) << 16);
}

// ------------- K_wct: wc[oc][c][3][3] -> split bf16 [oc][pos*64+c] -------------
__global__ void k_wct(const float* __restrict__ wc,
                      unsigned short* __restrict__ wh,
                      unsigned short* __restrict__ wl) {
    int idx = blockIdx.x*256 + threadIdx.x;   // 64*576 = 36864
    if (idx < 64*576) {
        int k = idx % 576;
        int oc = idx / 576;
        int pos = k >> 6;
        int c = k & 63;
        float v = wc[((size_t)oc*64 + c)*9 + pos];
        unsigned short h = bf16r(v);
        wh[idx] = h;
        wl[idx] = bf16r(v - bf16f(h));
    }
}

// ------------- K_wsplit: w0[oc][c][5][5] -> whT/wlT [tap][oc][c] bf16 split ----
__global__ void k_wsplit(const float* __restrict__ w0,
                         unsigned short* __restrict__ whT,
                         unsigned short* __restrict__ wlT) {
    int idx = blockIdx.x*256 + threadIdx.x;   // 25*64*64 = 102400
    if (idx < 25*64*64) {
        int c = idx & 63;
        int t = idx >> 6;
        int oc = t & 63;
        int tap = t >> 6;
        float v = w0[((size_t)oc*CC + c)*25 + tap];
        unsigned short h = bf16r(v);
        float l = v - bf16f(h);
        whT[idx] = h;
        wlT[idx] = bf16r(l);
    }
}

// ------------- K3: offset conv 3x3 -------------
__global__ __launch_bounds__(256) void k_off_conv(const float* __restrict__ img,
                                                  const float* __restrict__ wp,
                                                  const float* __restrict__ bp,
                                                  float* __restrict__ off) {
    int tid = threadIdx.x;
    int bid = blockIdx.x;
    int j = bid % WF;
    int t = bid / WF;
    int oc = t % 18;
    int b = t / 18;
    float acc = bp[oc];
    for (int c = 0; c < CC; ++c) {
        const float* ib = img + (size_t)(b*CC + c)*NPIX;
        const float* wb = wp + ((size_t)oc*CC + c)*9;
        #pragma unroll
        for (int dj = 0; dj < 3; ++dj) {
            int jj = j + dj - 1;
            if (jj < 0 || jj >= WF) continue;
            const float* col = ib + (size_t)jj*HH;
            #pragma unroll
            for (int di = 0; di < 3; ++di) {
                int ii = tid + di - 1;
                float v = (ii >= 0 && ii < HH) ? col[ii] : 0.f;
                acc += wb[di*3 + dj] * v;
            }
        }
    }
    off[((size_t)(b*18 + oc)*WF + j)*HH + tid] = acc;
}

// ------------- K4: deformable sampling + stride-3 conv via split-bf16 MFMA ----
// Block: 16 output pixels (i) x one j x all 64 oc. K = 576 (pos*64+c), split
// into chunk0 (pos 0..3, K=256) and chunk1 (pos 4..8, K=320) so the split-bf16
// S tile fits in 25.6 KB LDS -> 6 blocks/CU (was 3).
// Wave w: oc tile = w*16 + (lane&15); px = lane&15 on B side; 3-pass split MFMA.
#define SPAD 328
__global__ __launch_bounds__(256) void k_deform(const float* __restrict__ imgc,
                                                const float* __restrict__ off,
                                                const unsigned short* __restrict__ wh,
                                                const unsigned short* __restrict__ wl,
                                                float* __restrict__ out) {
    __shared__ int   cidx[4][144];
    __shared__ float cwgt[4][144];
    __shared__ __align__(16) unsigned short Sh[16][SPAD];
    __shared__ __align__(16) unsigned short Sl[16][SPAD];
    int tid = threadIdx.x;
    int bid = blockIdx.x;
    int it = bid & 15;
    int rest = bid >> 4;
    int j = rest % WF;
    int b = rest / WF;
    int i0 = it * 16;

    if (tid < 144) {
        int pix = tid / 9;
        int pos = tid % 9;
        int ki = pos / 3, kj = pos % 3;
        int i = i0 + pix;
        int r = 3*i + ki - 1;
        int s = 3*j + kj - 1;
        float g[4] = {0.f,0.f,0.f,0.f};
        int ix[4] = {-1,-1,-1,-1};
        if (r >= 0 && s >= 0) {
            int hq = r/3, nx = r%3;
            int wq = s/3, ny = s%3;
            int n = nx*3 + ny;
            float ox = off[((size_t)(b*18 + n)*WF + wq)*HH + hq];
            float oy = off[((size_t)(b*18 + 9 + n)*WF + wq)*HH + hq];
            float pxf = (float)(hq + nx) + ox;
            float pyf = (float)(wq + ny) + oy;
            float qx = floorf(pxf), qy = floorf(pyf);
            float qltx = fminf(fmaxf(qx, 0.f), 257.f);
            float qlty = fminf(fmaxf(qy, 0.f), 130.f);
            float qrbx = fminf(fmaxf(qx + 1.f, 0.f), 257.f);
            float qrby = fminf(fmaxf(qy + 1.f, 0.f), 130.f);
            float pxc = fminf(fmaxf(pxf, 0.f), 257.f);
            float pyc = fminf(fmaxf(pyf, 0.f), 130.f);
            float glt = (1.f + (qltx - pxc)) * (1.f + (qlty - pyc));
            float grb = (1.f - (qrbx - pxc)) * (1.f - (qrby - pyc));
            float glb = (1.f + (qltx - pxc)) * (1.f - (qrby - pyc));
            float grt = (1.f - (qrbx - pxc)) * (1.f + (qlty - pyc));
            int ax0 = (int)qltx, ax1 = (int)qrbx;
            int ay0 = (int)qlty, ay1 = (int)qrby;
            int cx[4] = {ax0, ax1, ax0, ax1};
            int cy[4] = {ay0, ay1, ay1, ay0};
            g[0]=glt; g[1]=grb; g[2]=glb; g[3]=grt;
            #pragma unroll
            for (int q = 0; q < 4; ++q) {
                int a = cx[q], bq = cy[q];
                ix[q] = (a >= 1 && a <= 256 && bq >= 1 && bq <= 129)
                        ? ((bq-1)*HH + (a-1))*CC : -1;
            }
        }
        #pragma unroll
        for (int q = 0; q < 4; ++q) { cidx[q][tid] = ix[q]; cwgt[q][tid] = g[q]; }
    }
    __syncthreads();

    const float* cb = imgc + (size_t)b * (size_t)WF * HH * CC;
    int lane = tid & 63;
    int w = tid >> 6;
    int l15 = lane & 15;
    int l4 = lane >> 4;
    float4v acc = {0.f, 0.f, 0.f, 0.f};
    const unsigned short* wbh = wh + (size_t)(w*16 + l15)*576 + l4*8;
    const unsigned short* wbl = wl + (size_t)(w*16 + l15)*576 + l4*8;

    // ---- chunk 0: pos 0..3 (K=256) ----
    for (int t = tid; t < 4096; t += 256) {
        int c = t & 63;
        int s = t >> 6;              // 0..63
        int pix = s >> 2, pos = s & 3;
        int combo = pix*9 + pos;
        float sum = 0.f;
        #pragma unroll
        for (int q = 0; q < 4; ++q) {
            int ofs = cidx[q][combo];
            float v = (ofs >= 0) ? cb[(size_t)ofs + c] : 0.f;
            sum += cwgt[q][combo] * v;
        }
        unsigned short h = bf16r(sum);
        Sh[pix][pos*64 + c] = h;
        Sl[pix][pos*64 + c] = bf16r(sum - bf16f(h));
    }
    __syncthreads();
    #pragma unroll
    for (int k0 = 0; k0 < 256; k0 += 32) {
        short8v Ah = *(const short8v*)&wbh[k0];
        short8v Al = *(const short8v*)&wbl[k0];
        short8v Bh = *(const short8v*)&Sh[l15][k0 + l4*8];
        short8v Bl = *(const short8v*)&Sl[l15][k0 + l4*8];
        acc = __builtin_amdgcn_mfma_f32_16x16x32_bf16(Ah, Bh, acc, 0, 0, 0);
        acc = __builtin_amdgcn_mfma_f32_16x16x32_bf16(Ah, Bl, acc, 0, 0, 0);
        acc = __builtin_amdgcn_mfma_f32_16x16x32_bf16(Al, Bh, acc, 0, 0, 0);
    }
    __syncthreads();

    // ---- chunk 1: pos 4..8 (K=320) ----
    for (int t = tid; t < 5120; t += 256) {
        int c = t & 63;
        int s = t >> 6;              // 0..79
        int pix = s / 5, pp = s - pix*5;
        int combo = pix*9 + 4 + pp;
        float sum = 0.f;
        #pragma unroll
        for (int q = 0; q < 4; ++q) {
            int ofs = cidx[q][combo];
            float v = (ofs >= 0) ? cb[(size_t)ofs + c] : 0.f;
            sum += cwgt[q][combo] * v;
        }
        unsigned short h = bf16r(sum);
        Sh[pix][pp*64 + c] = h;
        Sl[pix][pp*64 + c] = bf16r(sum - bf16f(h));
    }
    __syncthreads();
    #pragma unroll
    for (int k0 = 0; k0 < 320; k0 += 32) {
        short8v Ah = *(const short8v*)&wbh[256 + k0];
        short8v Al = *(const short8v*)&wbl[256 + k0];
        short8v Bh = *(const short8v*)&Sh[l15][k0 + l4*8];
        short8v Bl = *(const short8v*)&Sl[l15][k0 + l4*8];
        acc = __builtin_amdgcn_mfma_f32_16x16x32_bf16(Ah, Bh, acc, 0, 0, 0);
        acc = __builtin_amdgcn_mfma_f32_16x16x32_bf16(Ah, Bl, acc, 0, 0, 0);
        acc = __builtin_amdgcn_mfma_f32_16x16x32_bf16(Al, Bh, acc, 0, 0, 0);
    }

    // ---- epilogue: D[row=oc_local][col=px] ----
    size_t ob = (size_t)b*CC*NPIX + (size_t)j*HH + i0;
    #pragma unroll
    for (int r = 0; r < 4; ++r) {
        int oc = w*16 + l4*4 + r;
        out[ob + (size_t)oc*NPIX + l15] = acc[r];
    }
}

// ------------- K5: fused 1x1 convs + trig combine -------------
__global__ __launch_bounds__(256) void k_combine(const float* __restrict__ ampc,
                                                 const float* __restrict__ phac,
                                                 float* __restrict__ a3,
                                                 float* __restrict__ p3,
                                                 const float* __restrict__ w1a,
                                                 const float* __restrict__ b1a,
                                                 const float* __restrict__ w1p,
                                                 const float* __restrict__ b1p) {
    __shared__ float la[64][65], lp[64][65];
    int tid = threadIdx.x;
    int bid = blockIdx.x;
    int quarter = bid & 3;
    int rest = bid >> 2;
    int j = rest % WF;
    int b = rest / WF;
    int i0 = quarter * 64;
    size_t gbase = ((size_t)(b*WF + j)*HH + i0) * CC;
    for (int rep = 0; rep < 16; ++rep) {
        int t = rep*256 + tid;
        int pix = t >> 6;
        int c = t & 63;
        la[c][pix] = ampc[gbase + t];
        lp[c][pix] = phac[gbase + t];
    }
    __syncthreads();
    int ii = tid & 63;
    int wv = tid >> 6;
    float acc_a[16], acc_p[16];
    #pragma unroll
    for (int q = 0; q < 16; ++q) { acc_a[q] = b1a[wv*16+q]; acc_p[q] = b1p[wv*16+q]; }
    for (int c = 0; c < CC; ++c) {
        float av = la[c][ii], pv = lp[c][ii];
        #pragma unroll
        for (int q = 0; q < 16; ++q) {
            acc_a[q] += w1a[(wv*16+q)*CC + c] * av;
            acc_p[q] += w1p[(wv*16+q)*CC + c] * pv;
        }
    }
    #pragma unroll
    for (int q = 0; q < 16; ++q) {
        int oc = wv*16 + q;
        size_t idx = (size_t)(b*CC + oc)*NPIX + (size_t)j*HH + i0 + ii;
        float a3v = a3[idx];
        float p3v = p3[idx];
        float s1, c1, s3, c3;
        sincosf(acc_p[q], &s1, &c1);
        sincosf(p3v, &s3, &c3);
        float re = acc_a[q]*c3 + a3v*c1 + 3e-8f;
        float im = a3v*s1 + acc_a[q]*s3 + 2e-8f;
        a3[idx] = re;
        p3[idx] = im;
    }
}

// ------------- K6: inverse column fft -------------
__global__ __launch_bounds__(256) void k_ifft_cols(const float* __restrict__ ocre,
                                                   const float* __restrict__ ocim,
                                                   float* __restrict__ r2re,
                                                   float* __restrict__ r2im) {
    __shared__ float2 xs[256], ys[256];
    int t = threadIdx.x;
    int bid = blockIdx.x;
    int k = bid % WF;
    int bc = bid / WF;
    size_t base = ((size_t)bc*WF + k)*HH;
    xs[t] = make_float2(ocre[base + t], ocim[base + t]);
    __syncthreads();
    float2 X = fft256_lds<1>(xs, ys, t);
    size_t ob = ((size_t)bc*HH + t)*WF + k;
    r2re[ob] = X.x * (1.0f/256.0f);
    r2im[ob] = X.y * (1.0f/256.0f);
}

// ------------- K7: hermitian row irfft + abs -------------
__global__ __launch_bounds__(256) void k_irfft_rows(const float* __restrict__ r2re,
                                                    const float* __restrict__ r2im,
                                                    float* __restrict__ xr) {
    __shared__ float2 xs[256], ys[256];
    int t = threadIdx.x;
    int bid = blockIdx.x;
    int y = bid & 255;
    int bc = bid >> 8;
    size_t base = ((size_t)bc*HH + y)*WF;
    if (t < WF) xs[t] = make_float2(r2re[base + t], r2im[base + t]);
    __syncthreads();
    if (t >= WF) {
        float2 v = xs[256 - t];
        xs[t] = make_float2(v.x, -v.y);
    }
    __syncthreads();
    float2 X = fft256_lds<1>(xs, ys, t);
    xr[((size_t)bc*HH + y)*WW + t] = fabsf(X.x * (1.0f/256.0f));
}

// ------------- K_split: xr[b][c][y][x] fp32 -> xh/xl [b][ch][y][x][32c] bf16 ---
__global__ __launch_bounds__(256) void k_split(const float* __restrict__ xr,
                                               unsigned short* __restrict__ xh,
                                               unsigned short* __restrict__ xl) {
    __shared__ float tile[64][65];
    int tid = threadIdx.x;
    int bid = blockIdx.x;
    int q = bid & 3;
    int y = (bid >> 2) & 255;
    int b = bid >> 10;
    int x0 = q*64;
    int lane = tid & 63;
    int cg = tid >> 6;
    for (int rep = 0; rep < 16; ++rep) {
        int c = cg*16 + rep;
        tile[c][lane] = xr[(((size_t)(b*CC + c)*HH + y)*WW) + x0 + lane];
    }
    __syncthreads();
    int x = tid >> 2;
    int c0 = (tid & 3)*8;
    #pragma unroll
    for (int ch = 0; ch < 2; ++ch) {
        short8v hv, lv;
        #pragma unroll
        for (int j = 0; j < 8; ++j) {
            float v = tile[ch*32 + c0 + j][x];
            unsigned short h = bf16r(v);
            float l = v - bf16f(h);
            hv[j] = (short)h;
            lv[j] = (short)bf16r(l);
        }
        size_t ob = ((((size_t)(b*2 + ch)*HH + y)*WW) + x0 + x)*32 + c0;
        *(short8v*)&xh[ob] = hv;
        *(short8v*)&xl[ob] = lv;
    }
}

// ------------- K8: final 5x5 conv via split-bf16 MFMA -------------
#define LROW 40
#define LX 72
#define LROWS 6
#define PLANE (LROWS*LX*LROW)    // 17280 ushorts

__global__ __launch_bounds__(256) void k_conv5m(const unsigned short* __restrict__ xh,
                                                const unsigned short* __restrict__ xl,
                                                const unsigned short* __restrict__ whT,
                                                const unsigned short* __restrict__ wlT,
                                                const float* __restrict__ b0,
                                                float* __restrict__ out) {
    __shared__ unsigned short smem[2*PLANE];
    int tid = threadIdx.x;
    int bid = blockIdx.x;
    int q = bid & 3;
    int yb = (bid >> 2) & 127;
    int b = bid >> 9;
    int x0 = q*64;
    int y0 = yb*2;
    int lane = tid & 63;
    int w = tid >> 6;
    int wrow = w >> 1;          // output row within block (0..1)
    int oc0 = (w & 1)*32;       // oc half for this wave
    int l15 = lane & 15;
    int l4  = lane >> 4;

    float4v acc[2][4];
    #pragma unroll
    for (int o = 0; o < 2; ++o) {
        float4v bi;
        #pragma unroll
        for (int r = 0; r < 4; ++r) bi[r] = b0[oc0 + o*16 + l4*4 + r];
        #pragma unroll
        for (int p = 0; p < 4; ++p) acc[o][p] = bi;
    }

    for (int ch = 0; ch < 2; ++ch) {
        __syncthreads();
        #pragma unroll
        for (int plane = 0; plane < 2; ++plane) {
            const unsigned short* src = plane ? xl : xh;
            size_t gb = ((size_t)(b*2 + ch)*HH);
            for (int it = tid; it < LROWS*LX*4; it += 256) {   // 1728
                int part = it & 3;
                int s = it >> 2;
                int row = s / LX;
                int xi = s - row*LX;
                int gy = y0 + row - 2;
                int gx = x0 + xi - 2;
                short8v v = {0,0,0,0,0,0,0,0};
                if (gy >= 0 && gy < HH && gx >= 0 && gx < WW)
                    v = *(const short8v*)&src[((gb + gy)*WW + gx)*32 + part*8];
                *(short8v*)&smem[plane*PLANE + (row*LX + xi)*LROW + part*8] = v;
            }
        }
        __syncthreads();
        for (int tap = 0; tap < 25; ++tap) {
            int dy = tap/5, dx = tap - dy*5;
            size_t wb = ((size_t)tap*64 + oc0 + l15)*64 + ch*32 + l4*8;
            short8v Ah0 = *(const short8v*)&whT[wb];
            short8v Ah1 = *(const short8v*)&whT[wb + 16*64];
            short8v Al0 = *(const short8v*)&wlT[wb];
            short8v Al1 = *(const short8v*)&wlT[wb + 16*64];
            int rbase = (wrow + dy)*LX + l15 + dx;
            short8v Bh[4], Bl[4];
            #pragma unroll
            for (int p = 0; p < 4; ++p) {
                int a = (rbase + p*16)*LROW + l4*8;
                Bh[p] = *(const short8v*)&smem[a];
                Bl[p] = *(const short8v*)&smem[a + PLANE];
            }
            #pragma unroll
            for (int o = 0; o < 2; ++o) {
                short8v Ah = o ? Ah1 : Ah0;
                short8v Al = o ? Al1 : Al0;
                #pragma unroll
                for (int p = 0; p < 4; ++p) {
                    acc[o][p] = __builtin_amdgcn_mfma_f32_16x16x32_bf16(Ah, Bh[p], acc[o][p], 0, 0, 0);
                    acc[o][p] = __builtin_amdgcn_mfma_f32_16x16x32_bf16(Ah, Bl[p], acc[o][p], 0, 0, 0);
                    acc[o][p] = __builtin_amdgcn_mfma_f32_16x16x32_bf16(Al, Bh[p], acc[o][p], 0, 0, 0);
                }
            }
        }
    }

    int y = y0 + wrow;
    #pragma unroll
    for (int o = 0; o < 2; ++o) {
        #pragma unroll
        for (int p = 0; p < 4; ++p) {
            #pragma unroll
            for (int r = 0; r < 4; ++r) {
                int oc = oc0 + o*16 + l4*4 + r;
                int x = x0 + p*16 + l15;
                out[(((size_t)(b*CC + oc)*HH + y)*WW) + x] = acc[o][p][r];
            }
        }
    }
}

extern "C" void kernel_launch(void* const* d_in, const int* in_sizes, int n_in,
                              void* d_out, int out_size, void* d_ws, size_t ws_size,
                              hipStream_t stream) {
    const float* x    = (const float*)d_in[0];
    const float* wp_a = (const float*)d_in[1];
    const float* bp_a = (const float*)d_in[2];
    const float* wc_a = (const float*)d_in[3];
    const float* w1_a = (const float*)d_in[4];
    const float* b1_a = (const float*)d_in[5];
    const float* wp_p = (const float*)d_in[6];
    const float* bp_p = (const float*)d_in[7];
    const float* wc_p = (const float*)d_in[8];
    const float* w1_p = (const float*)d_in[9];
    const float* b1_p = (const float*)d_in[10];
    const float* w0   = (const float*)d_in[11];
    const float* b0   = (const float*)d_in[12];
    float* out = (float*)d_out;
    float* ws  = (float*)d_ws;

    float* R0 = ws;
    float* R1 = ws + 2*NS;
    float* R2 = ws + 4*NS;

    float* r1re = R0;
    float* r1im = R0 + NS;
    float* amp  = R1;
    float* pha  = R1 + NS;
    float* ampc = R0;
    float* phac = R0 + NS;
    size_t offsz = (size_t)BB*18*NPIX;
    float* offa = R2;
    float* offp = R2 + offsz;
    // split 3x3 deform weights: 4 planes of 64*576 ushorts
    unsigned short* wsp = (unsigned short*)(R2 + 2*offsz);
    unsigned short* whA = wsp;
    unsigned short* wlA = wsp + 36864;
    unsigned short* whP = wsp + 2*36864;
    unsigned short* wlP = wsp + 3*36864;
    // split 5x5 weights after (same place as before)
    unsigned short* whT = wsp + 4*36864;
    unsigned short* wlT = whT + 25*64*64;
    float* A3   = R1;
    float* P3   = R1 + NS;
    float* r2re = R0;
    float* r2im = R0 + NS;
    float* xrp  = R1;
    unsigned short* xhp = (unsigned short*)R0;
    unsigned short* xlp = xhp + (size_t)BB*2*HH*WW*32;

    k_wct<<<144, 256, 0, stream>>>(wc_a, whA, wlA);
    k_wct<<<144, 256, 0, stream>>>(wc_p, whP, wlP);
    k_wsplit<<<400, 256, 0, stream>>>(w0, whT, wlT);
    k_fft_rows<<<BB*CC*HH, 256, 0, stream>>>(x, r1re, r1im);
    k_fft_cols<<<BB*CC*WF, 256, 0, stream>>>(r1re, r1im, amp, pha);
    k_pack<<<BB*WF*4, 256, 0, stream>>>(amp, ampc);
    k_pack<<<BB*WF*4, 256, 0, stream>>>(pha, phac);
    k_off_conv<<<BB*18*WF, 256, 0, stream>>>(amp, wp_a, bp_a, offa);
    k_off_conv<<<BB*18*WF, 256, 0, stream>>>(pha, wp_p, bp_p, offp);
    k_deform<<<BB*WF*16, 256, 0, stream>>>(ampc, offa, whA, wlA, A3);
    k_deform<<<BB*WF*16, 256, 0, stream>>>(phac, offp, whP, wlP, P3);
    k_combine<<<BB*WF*4, 256, 0, stream>>>(ampc, phac, A3, P3, w1_a, b1_a, w1_p, b1_p);
    k_ifft_cols<<<BB*CC*WF, 256, 0, stream>>>(A3, P3, r2re, r2im);
    k_irfft_rows<<<BB*CC*HH, 256, 0, stream>>>(r2re, r2im, xrp);
    k_split<<<BB*HH*4, 256, 0, stream>>>(xrp, xhp, xlp);
    k_conv5m<<<BB*128*4, 256, 0, stream>>>(xhp, xlp, whT, wlT, b0, out);
}

// Round 4
// 1689.377 us; speedup vs baseline: 2.0820x; 1.2733x over previous
//
#include <hip/hip_runtime.h>
#include <math.h>

#define BB 4
#define CC 64
#define HH 256
#define WW 256
#define WF 129
#define NPIX (WF*HH)                 // 33024
#define NS ((size_t)BB*CC*NPIX)      // 8454144 floats per plane-set
#define TWOPI 6.283185307179586f

typedef __attribute__((ext_vector_type(8))) short short8v;
typedef __attribute__((ext_vector_type(4))) float float4v;

// ---------------- four-step 256-point complex FFT in LDS ----------------
__device__ __forceinline__ float2 cmulf(float2 a, float2 b) {
    return make_float2(a.x*b.x - a.y*b.y, a.x*b.y + a.y*b.x);
}

template<int SIGN>
__device__ __forceinline__ float2 fft256_lds(const float2* __restrict__ xs,
                                             float2* __restrict__ ys, int t) {
    int k1 = t & 15, n2 = t >> 4;
    float s1, c1;
    sincosf((float)SIGN * (TWOPI/16.f) * (float)k1, &s1, &c1);
    float2 rb = make_float2(c1, s1);
    float2 w = make_float2(1.f, 0.f);
    float2 acc = make_float2(0.f, 0.f);
    #pragma unroll
    for (int n1 = 0; n1 < 16; ++n1) {
        float2 v = xs[n1*16 + n2];
        acc.x = fmaf(v.x, w.x, fmaf(-v.y, w.y, acc.x));
        acc.y = fmaf(v.x, w.y, fmaf( v.y, w.x, acc.y));
        w = cmulf(w, rb);
    }
    float s2, c2;
    sincosf((float)SIGN * (TWOPI/256.f) * (float)(n2*k1), &s2, &c2);
    ys[t] = cmulf(acc, make_float2(c2, s2));
    __syncthreads();
    float s3, c3;
    sincosf((float)SIGN * (TWOPI/16.f) * (float)n2, &s3, &c3);
    float2 rb2 = make_float2(c3, s3);
    float2 w2 = make_float2(1.f, 0.f);
    float2 acc2 = make_float2(0.f, 0.f);
    #pragma unroll
    for (int m2 = 0; m2 < 16; ++m2) {
        float2 v = ys[m2*16 + k1];
        acc2.x = fmaf(v.x, w2.x, fmaf(-v.y, w2.y, acc2.x));
        acc2.y = fmaf(v.x, w2.y, fmaf( v.y, w2.x, acc2.y));
        w2 = cmulf(w2, rb2);
    }
    return acc2;
}

// ---------------- K1: row rfft ----------------
__global__ __launch_bounds__(256) void k_fft_rows(const float* __restrict__ x,
                                                  float* __restrict__ r1re,
                                                  float* __restrict__ r1im) {
    __shared__ float2 xs[256], ys[256];
    int t = threadIdx.x;
    int bid = blockIdx.x;
    int y = bid & 255;
    int bc = bid >> 8;
    xs[t] = make_float2(x[(size_t)bc*HH*WW + (size_t)y*WW + t], 0.f);
    __syncthreads();
    float2 X = fft256_lds<-1>(xs, ys, t);
    if (t < WF) {
        r1re[((size_t)bc*WF + t)*HH + y] = X.x;
        r1im[((size_t)bc*WF + t)*HH + y] = X.y;
    }
}

// ------------- K2: column fft + amp/pha -------------
__global__ __launch_bounds__(256) void k_fft_cols(const float* __restrict__ r1re,
                                                  const float* __restrict__ r1im,
                                                  float* __restrict__ amp,
                                                  float* __restrict__ pha) {
    __shared__ float2 xs[256], ys[256];
    int t = threadIdx.x;
    int bid = blockIdx.x;
    int k = bid % WF;
    int bc = bid / WF;
    size_t base = ((size_t)bc*WF + k)*HH;
    xs[t] = make_float2(r1re[base + t], r1im[base + t]);
    __syncthreads();
    float2 X = fft256_lds<-1>(xs, ys, t);
    amp[base + t] = sqrtf(X.x*X.x + X.y*X.y);
    pha[base + t] = atan2f(X.y, X.x);
}

// ------------- K_pack: [b,c,k,m] -> channel-innermost [b,k,m,c] -------------
__global__ __launch_bounds__(256) void k_pack(const float* __restrict__ src,
                                              float* __restrict__ dst) {
    __shared__ float tile[64][65];
    int tid = threadIdx.x;
    int bid = blockIdx.x;
    int it = bid & 3;
    int rest = bid >> 2;
    int k = rest % WF;
    int b = rest / WF;
    int i0 = it*64;
    int ii = tid & 63;
    int cg = tid >> 6;
    for (int rep = 0; rep < 16; ++rep) {
        int c = cg*16 + rep;
        tile[c][ii] = src[(size_t)(b*CC + c)*NPIX + (size_t)k*HH + i0 + ii];
    }
    __syncthreads();
    for (int rep = 0; rep < 16; ++rep) {
        int m = cg*16 + rep;
        dst[((size_t)(b*WF + k)*HH + i0 + m)*CC + ii] = tile[ii][m];
    }
}

// ------------- bf16 helpers -------------
__device__ __forceinline__ unsigned short bf16r(float f) {
    unsigned u = __float_as_uint(f);
    unsigned r = (u + 0x7FFFu + ((u >> 16) & 1u)) >> 16;
    return (unsigned short)r;
}
__device__ __forceinline__ float bf16f(unsigned short h) {
    return __uint_as_float(((unsigned)h) << 16);
}

// ------------- K_wct: wc[oc][c][3][3] -> split bf16 [oc][pos*64+c] -------------
__global__ void k_wct(const float* __restrict__ wc,
                      unsigned short* __restrict__ wh,
                      unsigned short* __restrict__ wl) {
    int idx = blockIdx.x*256 + threadIdx.x;   // 64*576 = 36864
    if (idx < 64*576) {
        int k = idx % 576;
        int oc = idx / 576;
        int pos = k >> 6;
        int c = k & 63;
        float v = wc[((size_t)oc*64 + c)*9 + pos];
        unsigned short h = bf16r(v);
        wh[idx] = h;
        wl[idx] = bf16r(v - bf16f(h));
    }
}

// ------------- K_wsplit: w0[oc][c][5][5] -> whT/wlT [tap][oc][c] bf16 split ----
__global__ void k_wsplit(const float* __restrict__ w0,
                         unsigned short* __restrict__ whT,
                         unsigned short* __restrict__ wlT) {
    int idx = blockIdx.x*256 + threadIdx.x;   // 25*64*64 = 102400
    if (idx < 25*64*64) {
        int c = idx & 63;
        int t = idx >> 6;
        int oc = t & 63;
        int tap = t >> 6;
        float v = w0[((size_t)oc*CC + c)*25 + tap];
        unsigned short h = bf16r(v);
        float l = v - bf16f(h);
        whT[idx] = h;
        wlT[idx] = bf16r(l);
    }
}

// ------------- K_wpt: wp[oc][c][3][3] -> wpt[c][oc*9+pos] (both planes) -------
__global__ void k_wpt(const float* __restrict__ wpa, const float* __restrict__ wpp,
                      float* __restrict__ wta, float* __restrict__ wtp) {
    int idx = blockIdx.x*256 + threadIdx.x;   // 64*162 = 10368
    if (idx < 64*162) {
        int c = idx / 162;
        int r = idx - c*162;       // oc*9 + pos
        int oc = r / 9, pos = r - oc*9;
        size_t s = ((size_t)oc*CC + c)*9 + pos;
        wta[idx] = wpa[s];
        wtp[idx] = wpp[s];
    }
}

// ------------- K3: offset conv 3x3, all 18 oc per block, both planes ----------
// grid = 2*BB*WF: sel = plane (amp/pha), block = (b, j); 256 threads = i.
// Image columns staged once per c (double-buffered); weights are wave-uniform
// contiguous scalars (s_load) from wpt[c][162]. Kills the 18x re-read of the
// old oc-per-block layout (FETCH 268 MB -> ~1x input).
__global__ __launch_bounds__(256) void k_off2(const float* __restrict__ amp,
                                              const float* __restrict__ pha,
                                              const float* __restrict__ wptA,
                                              const float* __restrict__ wptP,
                                              const float* __restrict__ bpA,
                                              const float* __restrict__ bpP,
                                              float* __restrict__ offa,
                                              float* __restrict__ offp) {
    __shared__ float colb[2][3][260];
    int tid = threadIdx.x;
    int bid = blockIdx.x;
    int sel = (bid >= BB*WF) ? 1 : 0;
    int rb = sel ? bid - BB*WF : bid;
    int j = rb % WF;
    int b = rb / WF;
    const float* img = sel ? pha : amp;
    const float* wpt = sel ? wptP : wptA;
    const float* bp  = sel ? bpP  : bpA;
    float* off = sel ? offp : offa;

    const float* ib = img + (size_t)b*CC*NPIX + (size_t)j*HH;
    bool jm = (j > 0), jp = (j < WF-1);

    float acc[18];
    #pragma unroll
    for (int o = 0; o < 18; ++o) acc[o] = bp[o];

    // zero pad entries (ii index 0 and 257) of both buffers, once
    if (tid < 12) {
        int bufi = tid & 1;
        int dj = (tid >> 1) % 3;
        int e = tid / 6;
        colb[bufi][dj][e ? 257 : 0] = 0.f;
    }
    // stage c = 0 into buffer 0
    {
        const float* cb = ib;
        colb[0][1][tid+1] = cb[tid];
        colb[0][0][tid+1] = jm ? cb[tid - HH] : 0.f;
        colb[0][2][tid+1] = jp ? cb[tid + HH] : 0.f;
    }
    __syncthreads();

    for (int c = 0; c < CC; ++c) {
        int cur = c & 1;
        if (c + 1 < CC) {
            const float* cb = ib + (size_t)(c+1)*NPIX;
            colb[cur^1][1][tid+1] = cb[tid];
            colb[cur^1][0][tid+1] = jm ? cb[tid - HH] : 0.f;
            colb[cur^1][2][tid+1] = jp ? cb[tid + HH] : 0.f;
        }
        float v[9];
        #pragma unroll
        for (int di = 0; di < 3; ++di)
            #pragma unroll
            for (int dj = 0; dj < 3; ++dj)
                v[di*3+dj] = colb[cur][dj][tid + di];
        const float* wc = wpt + c*162;
        #pragma unroll
        for (int o = 0; o < 18; ++o) {
            #pragma unroll
            for (int p = 0; p < 9; ++p)
                acc[o] = fmaf(wc[o*9+p], v[p], acc[o]);
        }
        __syncthreads();
    }

    size_t ob = ((size_t)(b*18)*WF + j)*HH + tid;
    #pragma unroll
    for (int o = 0; o < 18; ++o)
        off[ob + (size_t)o*WF*HH] = acc[o];
}

// ------------- K4: deformable sampling + stride-3 conv via split-bf16 MFMA ----
#define SPAD 328
__global__ __launch_bounds__(256) void k_deform(const float* __restrict__ imgc,
                                                const float* __restrict__ off,
                                                const unsigned short* __restrict__ wh,
                                                const unsigned short* __restrict__ wl,
                                                float* __restrict__ out) {
    __shared__ int   cidx[4][144];
    __shared__ float cwgt[4][144];
    __shared__ __align__(16) unsigned short Sh[16][SPAD];
    __shared__ __align__(16) unsigned short Sl[16][SPAD];
    int tid = threadIdx.x;
    int bid = blockIdx.x;
    int it = bid & 15;
    int rest = bid >> 4;
    int j = rest % WF;
    int b = rest / WF;
    int i0 = it * 16;

    if (tid < 144) {
        int pix = tid / 9;
        int pos = tid % 9;
        int ki = pos / 3, kj = pos % 3;
        int i = i0 + pix;
        int r = 3*i + ki - 1;
        int s = 3*j + kj - 1;
        float g[4] = {0.f,0.f,0.f,0.f};
        int ix[4] = {-1,-1,-1,-1};
        if (r >= 0 && s >= 0) {
            int hq = r/3, nx = r%3;
            int wq = s/3, ny = s%3;
            int n = nx*3 + ny;
            float ox = off[((size_t)(b*18 + n)*WF + wq)*HH + hq];
            float oy = off[((size_t)(b*18 + 9 + n)*WF + wq)*HH + hq];
            float pxf = (float)(hq + nx) + ox;
            float pyf = (float)(wq + ny) + oy;
            float qx = floorf(pxf), qy = floorf(pyf);
            float qltx = fminf(fmaxf(qx, 0.f), 257.f);
            float qlty = fminf(fmaxf(qy, 0.f), 130.f);
            float qrbx = fminf(fmaxf(qx + 1.f, 0.f), 257.f);
            float qrby = fminf(fmaxf(qy + 1.f, 0.f), 130.f);
            float pxc = fminf(fmaxf(pxf, 0.f), 257.f);
            float pyc = fminf(fmaxf(pyf, 0.f), 130.f);
            float glt = (1.f + (qltx - pxc)) * (1.f + (qlty - pyc));
            float grb = (1.f - (qrbx - pxc)) * (1.f - (qrby - pyc));
            float glb = (1.f + (qltx - pxc)) * (1.f - (qrby - pyc));
            float grt = (1.f - (qrbx - pxc)) * (1.f + (qlty - pyc));
            int ax0 = (int)qltx, ax1 = (int)qrbx;
            int ay0 = (int)qlty, ay1 = (int)qrby;
            int cx[4] = {ax0, ax1, ax0, ax1};
            int cy[4] = {ay0, ay1, ay1, ay0};
            g[0]=glt; g[1]=grb; g[2]=glb; g[3]=grt;
            #pragma unroll
            for (int q = 0; q < 4; ++q) {
                int a = cx[q], bq = cy[q];
                ix[q] = (a >= 1 && a <= 256 && bq >= 1 && bq <= 129)
                        ? ((bq-1)*HH + (a-1))*CC : -1;
            }
        }
        #pragma unroll
        for (int q = 0; q < 4; ++q) { cidx[q][tid] = ix[q]; cwgt[q][tid] = g[q]; }
    }
    __syncthreads();

    const float* cb = imgc + (size_t)b * (size_t)WF * HH * CC;
    int lane = tid & 63;
    int w = tid >> 6;
    int l15 = lane & 15;
    int l4 = lane >> 4;
    float4v acc = {0.f, 0.f, 0.f, 0.f};
    const unsigned short* wbh = wh + (size_t)(w*16 + l15)*576 + l4*8;
    const unsigned short* wbl = wl + (size_t)(w*16 + l15)*576 + l4*8;

    // ---- chunk 0: pos 0..3 (K=256) ----
    for (int t = tid; t < 4096; t += 256) {
        int c = t & 63;
        int s = t >> 6;              // 0..63
        int pix = s >> 2, pos = s & 3;
        int combo = pix*9 + pos;
        float sum = 0.f;
        #pragma unroll
        for (int q = 0; q < 4; ++q) {
            int ofs = cidx[q][combo];
            float v = (ofs >= 0) ? cb[(size_t)ofs + c] : 0.f;
            sum += cwgt[q][combo] * v;
        }
        unsigned short h = bf16r(sum);
        Sh[pix][pos*64 + c] = h;
        Sl[pix][pos*64 + c] = bf16r(sum - bf16f(h));
    }
    __syncthreads();
    #pragma unroll
    for (int k0 = 0; k0 < 256; k0 += 32) {
        short8v Ah = *(const short8v*)&wbh[k0];
        short8v Al = *(const short8v*)&wbl[k0];
        short8v Bh = *(const short8v*)&Sh[l15][k0 + l4*8];
        short8v Bl = *(const short8v*)&Sl[l15][k0 + l4*8];
        acc = __builtin_amdgcn_mfma_f32_16x16x32_bf16(Ah, Bh, acc, 0, 0, 0);
        acc = __builtin_amdgcn_mfma_f32_16x16x32_bf16(Ah, Bl, acc, 0, 0, 0);
        acc = __builtin_amdgcn_mfma_f32_16x16x32_bf16(Al, Bh, acc, 0, 0, 0);
    }
    __syncthreads();

    // ---- chunk 1: pos 4..8 (K=320) ----
    for (int t = tid; t < 5120; t += 256) {
        int c = t & 63;
        int s = t >> 6;              // 0..79
        int pix = s / 5, pp = s - pix*5;
        int combo = pix*9 + 4 + pp;
        float sum = 0.f;
        #pragma unroll
        for (int q = 0; q < 4; ++q) {
            int ofs = cidx[q][combo];
            float v = (ofs >= 0) ? cb[(size_t)ofs + c] : 0.f;
            sum += cwgt[q][combo] * v;
        }
        unsigned short h = bf16r(sum);
        Sh[pix][pp*64 + c] = h;
        Sl[pix][pp*64 + c] = bf16r(sum - bf16f(h));
    }
    __syncthreads();
    #pragma unroll
    for (int k0 = 0; k0 < 320; k0 += 32) {
        short8v Ah = *(const short8v*)&wbh[256 + k0];
        short8v Al = *(const short8v*)&wbl[256 + k0];
        short8v Bh = *(const short8v*)&Sh[l15][k0 + l4*8];
        short8v Bl = *(const short8v*)&Sl[l15][k0 + l4*8];
        acc = __builtin_amdgcn_mfma_f32_16x16x32_bf16(Ah, Bh, acc, 0, 0, 0);
        acc = __builtin_amdgcn_mfma_f32_16x16x32_bf16(Ah, Bl, acc, 0, 0, 0);
        acc = __builtin_amdgcn_mfma_f32_16x16x32_bf16(Al, Bh, acc, 0, 0, 0);
    }

    // ---- epilogue: D[row=oc_local][col=px] ----
    size_t ob = (size_t)b*CC*NPIX + (size_t)j*HH + i0;
    #pragma unroll
    for (int r = 0; r < 4; ++r) {
        int oc = w*16 + l4*4 + r;
        out[ob + (size_t)oc*NPIX + l15] = acc[r];
    }
}

// ------------- K5: fused 1x1 convs + trig combine -------------
__global__ __launch_bounds__(256) void k_combine(const float* __restrict__ ampc,
                                                 const float* __restrict__ phac,
                                                 float* __restrict__ a3,
                                                 float* __restrict__ p3,
                                                 const float* __restrict__ w1a,
                                                 const float* __restrict__ b1a,
                                                 const float* __restrict__ w1p,
                                                 const float* __restrict__ b1p) {
    __shared__ float la[64][65], lp[64][65];
    int tid = threadIdx.x;
    int bid = blockIdx.x;
    int quarter = bid & 3;
    int rest = bid >> 2;
    int j = rest % WF;
    int b = rest / WF;
    int i0 = quarter * 64;
    size_t gbase = ((size_t)(b*WF + j)*HH + i0) * CC;
    for (int rep = 0; rep < 16; ++rep) {
        int t = rep*256 + tid;
        int pix = t >> 6;
        int c = t & 63;
        la[c][pix] = ampc[gbase + t];
        lp[c][pix] = phac[gbase + t];
    }
    __syncthreads();
    int ii = tid & 63;
    int wv = tid >> 6;
    float acc_a[16], acc_p[16];
    #pragma unroll
    for (int q = 0; q < 16; ++q) { acc_a[q] = b1a[wv*16+q]; acc_p[q] = b1p[wv*16+q]; }
    for (int c = 0; c < CC; ++c) {
        float av = la[c][ii], pv = lp[c][ii];
        #pragma unroll
        for (int q = 0; q < 16; ++q) {
            acc_a[q] += w1a[(wv*16+q)*CC + c] * av;
            acc_p[q] += w1p[(wv*16+q)*CC + c] * pv;
        }
    }
    #pragma unroll
    for (int q = 0; q < 16; ++q) {
        int oc = wv*16 + q;
        size_t idx = (size_t)(b*CC + oc)*NPIX + (size_t)j*HH + i0 + ii;
        float a3v = a3[idx];
        float p3v = p3[idx];
        float s1, c1, s3, c3;
        sincosf(acc_p[q], &s1, &c1);
        sincosf(p3v, &s3, &c3);
        float re = acc_a[q]*c3 + a3v*c1 + 3e-8f;
        float im = a3v*s1 + acc_a[q]*s3 + 2e-8f;
        a3[idx] = re;
        p3[idx] = im;
    }
}

// ------------- K6: inverse column fft -------------
__global__ __launch_bounds__(256) void k_ifft_cols(const float* __restrict__ ocre,
                                                   const float* __restrict__ ocim,
                                                   float* __restrict__ r2re,
                                                   float* __restrict__ r2im) {
    __shared__ float2 xs[256], ys[256];
    int t = threadIdx.x;
    int bid = blockIdx.x;
    int k = bid % WF;
    int bc = bid / WF;
    size_t base = ((size_t)bc*WF + k)*HH;
    xs[t] = make_float2(ocre[base + t], ocim[base + t]);
    __syncthreads();
    float2 X = fft256_lds<1>(xs, ys, t);
    size_t ob = ((size_t)bc*HH + t)*WF + k;
    r2re[ob] = X.x * (1.0f/256.0f);
    r2im[ob] = X.y * (1.0f/256.0f);
}

// ------------- K7: hermitian row irfft + abs -------------
__global__ __launch_bounds__(256) void k_irfft_rows(const float* __restrict__ r2re,
                                                    const float* __restrict__ r2im,
                                                    float* __restrict__ xr) {
    __shared__ float2 xs[256], ys[256];
    int t = threadIdx.x;
    int bid = blockIdx.x;
    int y = bid & 255;
    int bc = bid >> 8;
    size_t base = ((size_t)bc*HH + y)*WF;
    if (t < WF) xs[t] = make_float2(r2re[base + t], r2im[base + t]);
    __syncthreads();
    if (t >= WF) {
        float2 v = xs[256 - t];
        xs[t] = make_float2(v.x, -v.y);
    }
    __syncthreads();
    float2 X = fft256_lds<1>(xs, ys, t);
    xr[((size_t)bc*HH + y)*WW + t] = fabsf(X.x * (1.0f/256.0f));
}

// ------------- K_split: xr[b][c][y][x] fp32 -> xh/xl [b][ch][y][x][32c] bf16 ---
__global__ __launch_bounds__(256) void k_split(const float* __restrict__ xr,
                                               unsigned short* __restrict__ xh,
                                               unsigned short* __restrict__ xl) {
    __shared__ float tile[64][65];
    int tid = threadIdx.x;
    int bid = blockIdx.x;
    int q = bid & 3;
    int y = (bid >> 2) & 255;
    int b = bid >> 10;
    int x0 = q*64;
    int lane = tid & 63;
    int cg = tid >> 6;
    for (int rep = 0; rep < 16; ++rep) {
        int c = cg*16 + rep;
        tile[c][lane] = xr[(((size_t)(b*CC + c)*HH + y)*WW) + x0 + lane];
    }
    __syncthreads();
    int x = tid >> 2;
    int c0 = (tid & 3)*8;
    #pragma unroll
    for (int ch = 0; ch < 2; ++ch) {
        short8v hv, lv;
        #pragma unroll
        for (int j = 0; j < 8; ++j) {
            float v = tile[ch*32 + c0 + j][x];
            unsigned short h = bf16r(v);
            float l = v - bf16f(h);
            hv[j] = (short)h;
            lv[j] = (short)bf16r(l);
        }
        size_t ob = ((((size_t)(b*2 + ch)*HH + y)*WW) + x0 + x)*32 + c0;
        *(short8v*)&xh[ob] = hv;
        *(short8v*)&xl[ob] = lv;
    }
}

// ------------- K8: final 5x5 conv via split-bf16 MFMA -------------
#define LROW 40
#define LX 72
#define LROWS 6
#define PLANE (LROWS*LX*LROW)    // 17280 ushorts

__global__ __launch_bounds__(256) void k_conv5m(const unsigned short* __restrict__ xh,
                                                const unsigned short* __restrict__ xl,
                                                const unsigned short* __restrict__ whT,
                                                const unsigned short* __restrict__ wlT,
                                                const float* __restrict__ b0,
                                                float* __restrict__ out) {
    __shared__ unsigned short smem[2*PLANE];
    int tid = threadIdx.x;
    int bid = blockIdx.x;
    int q = bid & 3;
    int yb = (bid >> 2) & 127;
    int b = bid >> 9;
    int x0 = q*64;
    int y0 = yb*2;
    int lane = tid & 63;
    int w = tid >> 6;
    int wrow = w >> 1;          // output row within block (0..1)
    int oc0 = (w & 1)*32;       // oc half for this wave
    int l15 = lane & 15;
    int l4  = lane >> 4;

    float4v acc[2][4];
    #pragma unroll
    for (int o = 0; o < 2; ++o) {
        float4v bi;
        #pragma unroll
        for (int r = 0; r < 4; ++r) bi[r] = b0[oc0 + o*16 + l4*4 + r];
        #pragma unroll
        for (int p = 0; p < 4; ++p) acc[o][p] = bi;
    }

    for (int ch = 0; ch < 2; ++ch) {
        __syncthreads();
        #pragma unroll
        for (int plane = 0; plane < 2; ++plane) {
            const unsigned short* src = plane ? xl : xh;
            size_t gb = ((size_t)(b*2 + ch)*HH);
            for (int it = tid; it < LROWS*LX*4; it += 256) {   // 1728
                int part = it & 3;
                int s = it >> 2;
                int row = s / LX;
                int xi = s - row*LX;
                int gy = y0 + row - 2;
                int gx = x0 + xi - 2;
                short8v v = {0,0,0,0,0,0,0,0};
                if (gy >= 0 && gy < HH && gx >= 0 && gx < WW)
                    v = *(const short8v*)&src[((gb + gy)*WW + gx)*32 + part*8];
                *(short8v*)&smem[plane*PLANE + (row*LX + xi)*LROW + part*8] = v;
            }
        }
        __syncthreads();
        for (int tap = 0; tap < 25; ++tap) {
            int dy = tap/5, dx = tap - dy*5;
            size_t wb = ((size_t)tap*64 + oc0 + l15)*64 + ch*32 + l4*8;
            short8v Ah0 = *(const short8v*)&whT[wb];
            short8v Ah1 = *(const short8v*)&whT[wb + 16*64];
            short8v Al0 = *(const short8v*)&wlT[wb];
            short8v Al1 = *(const short8v*)&wlT[wb + 16*64];
            int rbase = (wrow + dy)*LX + l15 + dx;
            short8v Bh[4], Bl[4];
            #pragma unroll
            for (int p = 0; p < 4; ++p) {
                int a = (rbase + p*16)*LROW + l4*8;
                Bh[p] = *(const short8v*)&smem[a];
                Bl[p] = *(const short8v*)&smem[a + PLANE];
            }
            #pragma unroll
            for (int o = 0; o < 2; ++o) {
                short8v Ah = o ? Ah1 : Ah0;
                short8v Al = o ? Al1 : Al0;
                #pragma unroll
                for (int p = 0; p < 4; ++p) {
                    acc[o][p] = __builtin_amdgcn_mfma_f32_16x16x32_bf16(Ah, Bh[p], acc[o][p], 0, 0, 0);
                    acc[o][p] = __builtin_amdgcn_mfma_f32_16x16x32_bf16(Ah, Bl[p], acc[o][p], 0, 0, 0);
                    acc[o][p] = __builtin_amdgcn_mfma_f32_16x16x32_bf16(Al, Bh[p], acc[o][p], 0, 0, 0);
                }
            }
        }
    }

    int y = y0 + wrow;
    #pragma unroll
    for (int o = 0; o < 2; ++o) {
        #pragma unroll
        for (int p = 0; p < 4; ++p) {
            #pragma unroll
            for (int r = 0; r < 4; ++r) {
                int oc = oc0 + o*16 + l4*4 + r;
                int x = x0 + p*16 + l15;
                out[(((size_t)(b*CC + oc)*HH + y)*WW) + x] = acc[o][p][r];
            }
        }
    }
}

extern "C" void kernel_launch(void* const* d_in, const int* in_sizes, int n_in,
                              void* d_out, int out_size, void* d_ws, size_t ws_size,
                              hipStream_t stream) {
    const float* x    = (const float*)d_in[0];
    const float* wp_a = (const float*)d_in[1];
    const float* bp_a = (const float*)d_in[2];
    const float* wc_a = (const float*)d_in[3];
    const float* w1_a = (const float*)d_in[4];
    const float* b1_a = (const float*)d_in[5];
    const float* wp_p = (const float*)d_in[6];
    const float* bp_p = (const float*)d_in[7];
    const float* wc_p = (const float*)d_in[8];
    const float* w1_p = (const float*)d_in[9];
    const float* b1_p = (const float*)d_in[10];
    const float* w0   = (const float*)d_in[11];
    const float* b0   = (const float*)d_in[12];
    float* out = (float*)d_out;
    float* ws  = (float*)d_ws;

    float* R0 = ws;
    float* R1 = ws + 2*NS;
    float* R2 = ws + 4*NS;

    float* r1re = R0;
    float* r1im = R0 + NS;
    float* amp  = R1;
    float* pha  = R1 + NS;
    float* ampc = R0;
    float* phac = R0 + NS;
    size_t offsz = (size_t)BB*18*NPIX;
    float* offa = R2;
    float* offp = R2 + offsz;
    // split 3x3 deform weights: 4 planes of 64*576 ushorts
    unsigned short* wsp = (unsigned short*)(R2 + 2*offsz);
    unsigned short* whA = wsp;
    unsigned short* wlA = wsp + 36864;
    unsigned short* whP = wsp + 2*36864;
    unsigned short* wlP = wsp + 3*36864;
    // split 5x5 weights after
    unsigned short* whT = wsp + 4*36864;
    unsigned short* wlT = whT + 25*64*64;
    // transposed offset-conv weights (fp32): 2 x 10368 floats
    float* wptA = (float*)(wlT + 25*64*64);
    float* wptP = wptA + 64*162;
    float* A3   = R1;
    float* P3   = R1 + NS;
    float* r2re = R0;
    float* r2im = R0 + NS;
    float* xrp  = R1;
    unsigned short* xhp = (unsigned short*)R0;
    unsigned short* xlp = xhp + (size_t)BB*2*HH*WW*32;

    k_wct<<<144, 256, 0, stream>>>(wc_a, whA, wlA);
    k_wct<<<144, 256, 0, stream>>>(wc_p, whP, wlP);
    k_wsplit<<<400, 256, 0, stream>>>(w0, whT, wlT);
    k_wpt<<<41, 256, 0, stream>>>(wp_a, wp_p, wptA, wptP);
    k_fft_rows<<<BB*CC*HH, 256, 0, stream>>>(x, r1re, r1im);
    k_fft_cols<<<BB*CC*WF, 256, 0, stream>>>(r1re, r1im, amp, pha);
    k_pack<<<BB*WF*4, 256, 0, stream>>>(amp, ampc);
    k_pack<<<BB*WF*4, 256, 0, stream>>>(pha, phac);
    k_off2<<<2*BB*WF, 256, 0, stream>>>(amp, pha, wptA, wptP, bp_a, bp_p, offa, offp);
    k_deform<<<BB*WF*16, 256, 0, stream>>>(ampc, offa, whA, wlA, A3);
    k_deform<<<BB*WF*16, 256, 0, stream>>>(phac, offp, whP, wlP, P3);
    k_combine<<<BB*WF*4, 256, 0, stream>>>(ampc, phac, A3, P3, w1_a, b1_a, w1_p, b1_p);
    k_ifft_cols<<<BB*CC*WF, 256, 0, stream>>>(A3, P3, r2re, r2im);
    k_irfft_rows<<<BB*CC*HH, 256, 0, stream>>>(r2re, r2im, xrp);
    k_split<<<BB*HH*4, 256, 0, stream>>>(xrp, xhp, xlp);
    k_conv5m<<<BB*128*4, 256, 0, stream>>>(xhp, xlp, whT, wlT, b0, out);
}